// Round 4
// baseline (282.648 us; speedup 1.0000x reference)
//
#include <hip/hip_runtime.h>

// Problem constants: B=8, L=1024, H=512, F=4
// out = gate * [x | alpha @ x],  gate = sigmoid([x|enc] @ W_gate)
// alpha = masked_softmax(max_f(Y_f Y_f^T)),  Y = relu(x @ W_proj)
//
// Round 4: explicit LDS double-buffering in all GEMM K-loops (prefetch tile
// t+1 during compute of tile t; one barrier/step). Round-3 analysis: fetch
// was ideal (33 MB) but 95% of each K-step was exposed load latency at
// 2 blocks/CU. Keep batch->XCD pinning (b = id&7) everywhere.

typedef _Float16 half8 __attribute__((ext_vector_type(8)));
typedef _Float16 half4 __attribute__((ext_vector_type(4)));
typedef float floatx4 __attribute__((ext_vector_type(4)));

typedef const __attribute__((address_space(1))) void* gas_ptr;
typedef __attribute__((address_space(3))) void* las_ptr;

// ---- shared GEMM tile machinery: BM=BN=128, BK=64, 256 threads (4 waves) ----
// LDS tile layout: row-major [128][64] fp16, 16B groups XOR-swizzled by (row&7)
// so ds_read_b128 fragment loads are <=2-way bank conflicted (free per m136),
// while global_load_lds keeps its required lane-contiguous LDS destinations.

__device__ __forceinline__ void stage_tile(_Float16* lds, const _Float16* src,
                                           int row0, int k0, int ld) {
  int t = threadIdx.x;
#pragma unroll
  for (int p = 0; p < 4; ++p) {
    int c = p * 256 + t;          // chunk 0..1023 (128 rows x 8 groups of 8 elems)
    int row = c >> 3;
    int kg = c & 7;
    int gk = (kg ^ (row & 7)) << 3;
    const _Float16* gp = src + (size_t)(row0 + row) * ld + (k0 + gk);
    __builtin_amdgcn_global_load_lds((gas_ptr)gp, (las_ptr)(lds + c * 8), 16, 0, 0);
  }
}

__device__ __forceinline__ half8 frag_ld(const _Float16* lds, int row, int g) {
  return *(const half8*)(lds + row * 64 + ((g ^ (row & 7)) << 3));
}

__device__ __forceinline__ void mfma_tile(const _Float16* lds_a, const _Float16* lds_b,
                                          floatx4 acc[4][4], int wm, int wn,
                                          int l16, int quad) {
#pragma unroll
  for (int kf = 0; kf < 2; ++kf) {
    half8 af[4], bf[4];
#pragma unroll
    for (int i = 0; i < 4; ++i) af[i] = frag_ld(lds_a, wm * 64 + i * 16 + l16, kf * 4 + quad);
#pragma unroll
    for (int i = 0; i < 4; ++i) bf[i] = frag_ld(lds_b, wn * 64 + i * 16 + l16, kf * 4 + quad);
#pragma unroll
    for (int mi = 0; mi < 4; ++mi)
#pragma unroll
      for (int ni = 0; ni < 4; ++ni)
        acc[mi][ni] = __builtin_amdgcn_mfma_f32_16x16x32_f16(af[mi], bf[ni], acc[mi][ni], 0, 0, 0);
  }
}

#define ZERO_ACC(acc)                                   \
  _Pragma("unroll") for (int mi = 0; mi < 4; ++mi)      \
  _Pragma("unroll") for (int ni = 0; ni < 4; ++ni)      \
  _Pragma("unroll") for (int r = 0; r < 4; ++r) acc[mi][ni][r] = 0.0f;

// ---- pre-pass: casts / transposes ----

__global__ void cast_kernel(const float* __restrict__ in, _Float16* __restrict__ out) {
  int i = blockIdx.x * 256 + threadIdx.x;
  float4 v = ((const float4*)in)[i];
  half4 h;
  h[0] = (_Float16)v.x; h[1] = (_Float16)v.y; h[2] = (_Float16)v.z; h[3] = (_Float16)v.w;
  ((half4*)out)[i] = h;
}

// in (batch,R,C) fp32 -> out (batch,C,R) fp16
__global__ void transpose_cast_kernel(const float* __restrict__ in, _Float16* __restrict__ out,
                                      int R, int C) {
  __shared__ float tile[32][33];
  int c0 = blockIdx.x * 32, r0 = blockIdx.y * 32;
  size_t boff = (size_t)blockIdx.z * R * C;
  in += boff; out += boff;
  int tx = threadIdx.x & 31, ty = threadIdx.x >> 5;  // 32 x 8
#pragma unroll
  for (int i = 0; i < 32; i += 8)
    tile[ty + i][tx] = in[(size_t)(r0 + ty + i) * C + c0 + tx];
  __syncthreads();
#pragma unroll
  for (int i = 0; i < 32; i += 8)
    out[(size_t)(c0 + ty + i) * R + r0 + tx] = (_Float16)tile[tx][ty + i];
}

// ---- K1: y = relu(x @ W_proj + b_proj) -> y_t (B,F,L,H) fp16 ----
// x16 (8192,512), WpT (2048,512); M=8192 N=2048 K=512

__global__ __launch_bounds__(256) void proj_kernel(const _Float16* __restrict__ x16,
                                                   const _Float16* __restrict__ WpT,
                                                   const float* __restrict__ bp,
                                                   _Float16* __restrict__ y_t) {
  __shared__ __align__(16) _Float16 lds_a[2][128 * 64];
  __shared__ __align__(16) _Float16 lds_b[2][128 * 64];
  int i0 = blockIdx.x * 128, n0 = blockIdx.y * 128;
  int t = threadIdx.x, lane = t & 63, w = t >> 6;
  int wm = w >> 1, wn = w & 1, quad = lane >> 4, l16 = lane & 15;
  floatx4 acc[4][4];
  ZERO_ACC(acc);
  stage_tile(lds_a[0], x16, i0, 0, 512);
  stage_tile(lds_b[0], WpT, n0, 0, 512);
  int cur = 0;
#pragma unroll 1
  for (int kt = 0; kt < 8; ++kt) {
    __syncthreads();
    if (kt < 7) {
      stage_tile(lds_a[cur ^ 1], x16, i0, (kt + 1) * 64, 512);
      stage_tile(lds_b[cur ^ 1], WpT, n0, (kt + 1) * 64, 512);
    }
    mfma_tile(lds_a[cur], lds_b[cur], acc, wm, wn, l16, quad);
    cur ^= 1;
  }
#pragma unroll
  for (int mi = 0; mi < 4; ++mi)
#pragma unroll
    for (int ni = 0; ni < 4; ++ni)
#pragma unroll
      for (int r = 0; r < 4; ++r) {
        int gr = i0 + wm * 64 + mi * 16 + quad * 4 + r;   // 0..8191
        int gc = n0 + wn * 64 + ni * 16 + l16;            // 0..2047
        float c = fmaxf(acc[mi][ni][r] + bp[gc], 0.0f);
        int b = gr >> 10, l = gr & 1023;
        int f = gc & 3, h = gc >> 2;
        y_t[(((size_t)(b * 4 + f)) * 1024 + l) * 512 + h] = (_Float16)c;
      }
}

// ---- K2: S[b,i,j] = max_f sum_h Y_f[i,h] Y_f[j,h] ----
// 512 blocks 1D, b = id & 7 (XCD pin; proven fetch-ideal in r3). f-loop and
// k-loop flattened into one 32-step double-buffered pipeline so prefetch
// crosses f-boundaries; smax fold is VALU work overlapping in-flight loads.

__global__ __launch_bounds__(256) void score_kernel(const _Float16* __restrict__ y_t,
                                                    float* __restrict__ S) {
  __shared__ __align__(16) _Float16 lds_a[2][128 * 64];
  __shared__ __align__(16) _Float16 lds_b[2][128 * 64];
  int id = blockIdx.x;
  int b = id & 7;
  int tile = id >> 3;          // 0..63
  int i0 = (tile >> 3) * 128, j0 = (tile & 7) * 128;
  int t = threadIdx.x, lane = t & 63, w = t >> 6;
  int wm = w >> 1, wn = w & 1, quad = lane >> 4, l16 = lane & 15;
  const _Float16* base = y_t + (size_t)b * 4 * 1024 * 512;
  floatx4 acc[4][4], smax[4][4];
  ZERO_ACC(acc);
  stage_tile(lds_a[0], base, i0, 0, 512);
  stage_tile(lds_b[0], base, j0, 0, 512);
  int cur = 0;
#pragma unroll 1
  for (int step = 0; step < 32; ++step) {   // step = f*8 + kt
    __syncthreads();
    int nxt = step + 1;
    if (nxt < 32) {
      const _Float16* pl = base + (size_t)(nxt >> 3) * (1024 * 512);
      int k0 = (nxt & 7) * 64;
      stage_tile(lds_a[cur ^ 1], pl, i0, k0, 512);
      stage_tile(lds_b[cur ^ 1], pl, j0, k0, 512);
    }
    mfma_tile(lds_a[cur], lds_b[cur], acc, wm, wn, l16, quad);
    if ((step & 7) == 7) {
      if (step == 7) {
#pragma unroll
        for (int mi = 0; mi < 4; ++mi)
#pragma unroll
          for (int ni = 0; ni < 4; ++ni) smax[mi][ni] = acc[mi][ni];
      } else {
#pragma unroll
        for (int mi = 0; mi < 4; ++mi)
#pragma unroll
          for (int ni = 0; ni < 4; ++ni)
#pragma unroll
            for (int r = 0; r < 4; ++r)
              smax[mi][ni][r] = fmaxf(smax[mi][ni][r], acc[mi][ni][r]);
      }
      ZERO_ACC(acc);
    }
    cur ^= 1;
  }
  float* Sb = S + (size_t)b * 1024 * 1024;
#pragma unroll
  for (int mi = 0; mi < 4; ++mi)
#pragma unroll
    for (int ni = 0; ni < 4; ++ni)
#pragma unroll
      for (int r = 0; r < 4; ++r) {
        int gi = i0 + wm * 64 + mi * 16 + quad * 4 + r;
        int gj = j0 + wn * 64 + ni * 16 + l16;
        Sb[(size_t)gi * 1024 + gj] = smax[mi][ni][r];
      }
}

// ---- K3: allennlp masked softmax per row -> alpha fp16 ----
// p = softmax(logits*m) (masked entries participate as 0), alpha = p*m/(sum(p*m)+1e-13)

__global__ __launch_bounds__(256) void softmax_kernel(const float* __restrict__ S,
                                                      const int* __restrict__ xmask,
                                                      _Float16* __restrict__ alpha) {
  __shared__ float red[16];
  int row = blockIdx.x;               // 0..8191
  int b = row >> 10, l = row & 1023;
  const float* sr = S + (size_t)row * 1024;
  const int* mr = xmask + b * 1024;
  int t = threadIdx.x, lane = t & 63, wid = t >> 6;
  int rm = mr[l];
  float v[4], mm[4];
  float vmax = 0.0f;  // masked entries are exactly 0, so max >= 0 always
#pragma unroll
  for (int q = 0; q < 4; ++q) {
    int i = t + q * 256;
    int m = (rm && mr[i] && (i != l)) ? 1 : 0;
    mm[q] = (float)m;
    v[q] = m ? sr[i] : 0.0f;
    vmax = fmaxf(vmax, v[q]);
  }
  for (int off = 32; off; off >>= 1) vmax = fmaxf(vmax, __shfl_down(vmax, off));
  if (lane == 0) red[wid] = vmax;
  __syncthreads();
  if (t == 0) red[8] = fmaxf(fmaxf(red[0], red[1]), fmaxf(red[2], red[3]));
  __syncthreads();
  vmax = red[8];
  float e[4], E = 0.0f, E2 = 0.0f;
#pragma unroll
  for (int q = 0; q < 4; ++q) {
    e[q] = expf(v[q] - vmax);
    E += e[q];
    E2 += e[q] * mm[q];
  }
  for (int off = 32; off; off >>= 1) {
    E += __shfl_down(E, off);
    E2 += __shfl_down(E2, off);
  }
  if (lane == 0) { red[wid] = E; red[4 + wid] = E2; }
  __syncthreads();
  if (t == 0) {
    red[9] = red[0] + red[1] + red[2] + red[3];
    red[10] = red[4] + red[5] + red[6] + red[7];
  }
  __syncthreads();
  E = red[9]; E2 = red[10];
  // alpha_i = (e_i/E)*m_i / (E2/E + 1e-13) = e_i*m_i / (E2 + 1e-13*E)
  float inv = 1.0f / (E2 + 1e-13f * E);
  _Float16* ar = alpha + (size_t)row * 1024;
#pragma unroll
  for (int q = 0; q < 4; ++q) {
    int i = t + q * 256;
    ar[i] = (_Float16)(e[q] * mm[q] * inv);
  }
}

// ---- K4: enc[b] = alpha[b] @ x[b]  (uses xT (B,H,L) as B-operand) ----
// 1D grid of 256, b = id & 7 (XCD pin; per-batch alpha(2MB)+xT(1MB) fits L2)

__global__ __launch_bounds__(256) void attn_kernel(const _Float16* __restrict__ alpha,
                                                   const _Float16* __restrict__ xT,
                                                   _Float16* __restrict__ enc) {
  __shared__ __align__(16) _Float16 lds_a[2][128 * 64];
  __shared__ __align__(16) _Float16 lds_b[2][128 * 64];
  int id = blockIdx.x;
  int b = id & 7;
  int tile = id >> 3;               // 0..31
  int i0 = (tile >> 2) * 128;       // 8 i-tiles
  int n0 = (tile & 3) * 128;        // 4 n-tiles
  const _Float16* A = alpha + (size_t)b * 1024 * 1024;
  const _Float16* Bm = xT + (size_t)b * 512 * 1024;
  int t = threadIdx.x, lane = t & 63, w = t >> 6;
  int wm = w >> 1, wn = w & 1, quad = lane >> 4, l16 = lane & 15;
  floatx4 acc[4][4];
  ZERO_ACC(acc);
  stage_tile(lds_a[0], A, i0, 0, 1024);
  stage_tile(lds_b[0], Bm, n0, 0, 1024);
  int cur = 0;
#pragma unroll 1
  for (int kt = 0; kt < 16; ++kt) {
    __syncthreads();
    if (kt < 15) {
      stage_tile(lds_a[cur ^ 1], A, i0, (kt + 1) * 64, 1024);
      stage_tile(lds_b[cur ^ 1], Bm, n0, (kt + 1) * 64, 1024);
    }
    mfma_tile(lds_a[cur], lds_b[cur], acc, wm, wn, l16, quad);
    cur ^= 1;
  }
  _Float16* eb = enc + (size_t)b * 1024 * 512;
#pragma unroll
  for (int mi = 0; mi < 4; ++mi)
#pragma unroll
    for (int ni = 0; ni < 4; ++ni)
#pragma unroll
      for (int r = 0; r < 4; ++r) {
        int gr = i0 + wm * 64 + mi * 16 + quad * 4 + r;  // l
        int gc = n0 + wn * 64 + ni * 16 + l16;           // h
        eb[(size_t)gr * 512 + gc] = (_Float16)acc[mi][ni][r];
      }
}

// ---- K5: gate = sigmoid([x|enc] @ W_gate + b_gate); out = gate*[x16|enc] ----
// grid (64, 8): i0 on x so XCD k caches only A-tiles i0 % 8 == k + all of B (2 MB)

__global__ __launch_bounds__(256) void gate_kernel(const _Float16* __restrict__ x16,
                                                   const _Float16* __restrict__ enc,
                                                   const _Float16* __restrict__ WgT,
                                                   const float* __restrict__ bg,
                                                   float* __restrict__ out) {
  __shared__ __align__(16) _Float16 lds_a[2][128 * 64];
  __shared__ __align__(16) _Float16 lds_b[2][128 * 64];
  int i0 = blockIdx.x * 128, n0 = blockIdx.y * 128;
  int t = threadIdx.x, lane = t & 63, w = t >> 6;
  int wm = w >> 1, wn = w & 1, quad = lane >> 4, l16 = lane & 15;
  floatx4 acc[4][4];
  ZERO_ACC(acc);
  stage_tile(lds_a[0], x16, i0, 0, 512);
  stage_tile(lds_b[0], WgT, n0, 0, 1024);
  int cur = 0;
#pragma unroll 1
  for (int kt = 0; kt < 16; ++kt) {
    __syncthreads();
    if (kt < 15) {
      int nk = kt + 1;
      if (nk < 8) stage_tile(lds_a[cur ^ 1], x16, i0, nk * 64, 512);
      else        stage_tile(lds_a[cur ^ 1], enc, i0, (nk - 8) * 64, 512);
      stage_tile(lds_b[cur ^ 1], WgT, n0, nk * 64, 1024);
    }
    mfma_tile(lds_a[cur], lds_b[cur], acc, wm, wn, l16, quad);
    cur ^= 1;
  }
#pragma unroll
  for (int mi = 0; mi < 4; ++mi)
#pragma unroll
    for (int ni = 0; ni < 4; ++ni)
#pragma unroll
      for (int r = 0; r < 4; ++r) {
        int gr = i0 + wm * 64 + mi * 16 + quad * 4 + r;  // 0..8191
        int gc = n0 + wn * 64 + ni * 16 + l16;           // 0..1023
        float c = acc[mi][ni][r] + bg[gc];
        float g = 1.0f / (1.0f + expf(-c));
        float jv = (gc < 512) ? (float)x16[(size_t)gr * 512 + gc]
                              : (float)enc[(size_t)gr * 512 + (gc - 512)];
        out[(size_t)gr * 1024 + gc] = g * jv;
      }
}

// ---- launch ----

extern "C" void kernel_launch(void* const* d_in, const int* in_sizes, int n_in,
                              void* d_out, int out_size, void* d_ws, size_t ws_size,
                              hipStream_t stream) {
  const float* x  = (const float*)d_in[0];   // (8,1024,512)
  const int* xm   = (const int*)d_in[1];     // (8,1024)
  const float* Wp = (const float*)d_in[2];   // (512,2048)
  const float* bp = (const float*)d_in[3];   // (2048)
  const float* Wg = (const float*)d_in[4];   // (1024,1024)
  const float* bg = (const float*)d_in[5];   // (1024)
  float* out = (float*)d_out;

  char* ws = (char*)d_ws;
  const size_t MB = 1024 * 1024;
  _Float16* x16 = (_Float16*)(ws);            // 8 MB  (8192,512)
  _Float16* xT  = (_Float16*)(ws + 8 * MB);   // 8 MB  (8,512,1024)
  _Float16* WpT = (_Float16*)(ws + 16 * MB);  // 2 MB  (2048,512)
  _Float16* WgT = (_Float16*)(ws + 18 * MB);  // 2 MB  (1024,1024)
  _Float16* y_t = (_Float16*)(ws + 20 * MB);  // 32 MB (8,4,1024,512)
  float*    S   = (float*)(ws + 52 * MB);     // 32 MB (8,1024,1024)  [end: 84 MB]
  // y_t is dead after score_kernel: alias alpha/enc onto it
  _Float16* alpha = (_Float16*)(ws + 20 * MB); // 16 MB (8,1024,1024)
  _Float16* enc   = (_Float16*)(ws + 36 * MB); // 8 MB  (8,1024,512)

  cast_kernel<<<4096, 256, 0, stream>>>(x, x16);
  transpose_cast_kernel<<<dim3(16, 32, 8), 256, 0, stream>>>(x, xT, 1024, 512);
  transpose_cast_kernel<<<dim3(64, 16, 1), 256, 0, stream>>>(Wp, WpT, 512, 2048);
  transpose_cast_kernel<<<dim3(32, 32, 1), 256, 0, stream>>>(Wg, WgT, 1024, 1024);

  proj_kernel<<<dim3(64, 16), 256, 0, stream>>>(x16, WpT, bp, y_t);
  score_kernel<<<512, 256, 0, stream>>>(y_t, S);
  softmax_kernel<<<8192, 256, 0, stream>>>(S, xm, alpha);
  attn_kernel<<<256, 256, 0, stream>>>(alpha, xT, enc);
  gate_kernel<<<dim3(64, 8), 256, 0, stream>>>(x16, enc, WgT, bg, out);
}

// Round 6
// 257.513 us; speedup vs baseline: 1.0976x; 1.0976x over previous
//
#include <hip/hip_runtime.h>

// Problem constants: B=8, L=1024, H=512, F=4
// out = gate * [x | alpha @ x],  gate = sigmoid([x|enc] @ W_gate)
// alpha = masked_softmax(max_f(Y_f Y_f^T)),  Y = relu(x @ W_proj)
//
// Round 6: precomputed staging pointers bumped +64 elems/step (offset imm of
// global_load_lds stays 0 — r5's nonzero-imm use produced NaN: unverified
// field semantics). Keep dbuf + batch->XCD pinning (fetch ideal since r3).

typedef _Float16 half8 __attribute__((ext_vector_type(8)));
typedef _Float16 half4 __attribute__((ext_vector_type(4)));
typedef float floatx4 __attribute__((ext_vector_type(4)));

typedef const __attribute__((address_space(1))) void* gas_ptr;
typedef __attribute__((address_space(3))) void* las_ptr;

// ---- shared GEMM tile machinery: BM=BN=128, BK=64, 256 threads (4 waves) ----
// LDS tile layout: row-major [128][64] fp16, 16B groups XOR-swizzled by (row&7)
// so ds_read_b128 fragment loads are <=2-way bank conflicted (free per m136),
// while global_load_lds keeps its required lane-contiguous LDS destinations.
// Staging: chunk c = p*256+t covers row=c>>3, group kg=c&7; global col =
// (kg^(row&7))*8; LDS dst = c*16 B (wave-uniform base + lane*16 contract).

__device__ __forceinline__ void init_stage_ptrs(const _Float16* src, int row0, int ld,
                                                const _Float16* gp[4]) {
  int t = threadIdx.x;
#pragma unroll
  for (int p = 0; p < 4; ++p) {
    int c = p * 256 + t;
    int row = c >> 3;
    int kg = c & 7;
    int gk = (kg ^ (row & 7)) << 3;
    gp[p] = src + (size_t)(row0 + row) * ld + gk;
  }
}

__device__ __forceinline__ void stage4(const _Float16* const gp[4],
                                       _Float16* ldsbuf, int lofs) {
#pragma unroll
  for (int p = 0; p < 4; ++p)
    __builtin_amdgcn_global_load_lds((gas_ptr)gp[p],
                                     (las_ptr)(ldsbuf + lofs + p * 2048), 16, 0, 0);
}

__device__ __forceinline__ void bump(const _Float16* gp[4], int d) {
#pragma unroll
  for (int p = 0; p < 4; ++p) gp[p] += d;
}

__device__ __forceinline__ half8 frag_ld(const _Float16* lds, int row, int g) {
  return *(const half8*)(lds + row * 64 + ((g ^ (row & 7)) << 3));
}

__device__ __forceinline__ void mfma_tile(const _Float16* lds_a, const _Float16* lds_b,
                                          floatx4 acc[4][4], int wm, int wn,
                                          int l16, int quad) {
#pragma unroll
  for (int kf = 0; kf < 2; ++kf) {
    half8 af[4], bf[4];
#pragma unroll
    for (int i = 0; i < 4; ++i) af[i] = frag_ld(lds_a, wm * 64 + i * 16 + l16, kf * 4 + quad);
#pragma unroll
    for (int i = 0; i < 4; ++i) bf[i] = frag_ld(lds_b, wn * 64 + i * 16 + l16, kf * 4 + quad);
#pragma unroll
    for (int mi = 0; mi < 4; ++mi)
#pragma unroll
      for (int ni = 0; ni < 4; ++ni)
        acc[mi][ni] = __builtin_amdgcn_mfma_f32_16x16x32_f16(af[mi], bf[ni], acc[mi][ni], 0, 0, 0);
  }
}

#define ZERO_ACC(acc)                                   \
  _Pragma("unroll") for (int mi = 0; mi < 4; ++mi)      \
  _Pragma("unroll") for (int ni = 0; ni < 4; ++ni)      \
  _Pragma("unroll") for (int r = 0; r < 4; ++r) acc[mi][ni][r] = 0.0f;

// ---- pre-pass: casts / transposes ----

__global__ void cast_kernel(const float* __restrict__ in, _Float16* __restrict__ out) {
  int i = blockIdx.x * 256 + threadIdx.x;
  float4 v = ((const float4*)in)[i];
  half4 h;
  h[0] = (_Float16)v.x; h[1] = (_Float16)v.y; h[2] = (_Float16)v.z; h[3] = (_Float16)v.w;
  ((half4*)out)[i] = h;
}

// in (batch,R,C) fp32 -> out (batch,C,R) fp16
__global__ void transpose_cast_kernel(const float* __restrict__ in, _Float16* __restrict__ out,
                                      int R, int C) {
  __shared__ float tile[32][33];
  int c0 = blockIdx.x * 32, r0 = blockIdx.y * 32;
  size_t boff = (size_t)blockIdx.z * R * C;
  in += boff; out += boff;
  int tx = threadIdx.x & 31, ty = threadIdx.x >> 5;  // 32 x 8
#pragma unroll
  for (int i = 0; i < 32; i += 8)
    tile[ty + i][tx] = in[(size_t)(r0 + ty + i) * C + c0 + tx];
  __syncthreads();
#pragma unroll
  for (int i = 0; i < 32; i += 8)
    out[(size_t)(c0 + ty + i) * R + r0 + tx] = (_Float16)tile[tx][ty + i];
}

// ---- K1: y = relu(x @ W_proj + b_proj) -> y_t (B,F,L,H) fp16 ----
// x16 (8192,512), WpT (2048,512); M=8192 N=2048 K=512

__global__ __launch_bounds__(256) void proj_kernel(const _Float16* __restrict__ x16,
                                                   const _Float16* __restrict__ WpT,
                                                   const float* __restrict__ bp,
                                                   _Float16* __restrict__ y_t) {
  __shared__ __align__(16) _Float16 ldsA[2][128 * 64];
  __shared__ __align__(16) _Float16 ldsB[2][128 * 64];
  int i0 = blockIdx.x * 128, n0 = blockIdx.y * 128;
  int t = threadIdx.x, lane = t & 63, w = t >> 6;
  int wm = w >> 1, wn = w & 1, quad = lane >> 4, l16 = lane & 15;
  int lofs = t * 8;
  const _Float16* gpA[4]; const _Float16* gpB[4];
  init_stage_ptrs(x16, i0, 512, gpA);
  init_stage_ptrs(WpT, n0, 512, gpB);
  floatx4 acc[4][4];
  ZERO_ACC(acc);
  stage4(gpA, ldsA[0], lofs); bump(gpA, 64);
  stage4(gpB, ldsB[0], lofs); bump(gpB, 64);
#pragma unroll 1
  for (int kt = 0; kt < 8; ++kt) {
    __syncthreads();
    if (kt < 7) {
      stage4(gpA, ldsA[(kt + 1) & 1], lofs); bump(gpA, 64);
      stage4(gpB, ldsB[(kt + 1) & 1], lofs); bump(gpB, 64);
    }
    mfma_tile(ldsA[kt & 1], ldsB[kt & 1], acc, wm, wn, l16, quad);
  }
#pragma unroll
  for (int mi = 0; mi < 4; ++mi)
#pragma unroll
    for (int ni = 0; ni < 4; ++ni)
#pragma unroll
      for (int r = 0; r < 4; ++r) {
        int gr = i0 + wm * 64 + mi * 16 + quad * 4 + r;   // 0..8191
        int gc = n0 + wn * 64 + ni * 16 + l16;            // 0..2047
        float c = fmaxf(acc[mi][ni][r] + bp[gc], 0.0f);
        int b = gr >> 10, l = gr & 1023;
        int f = gc & 3, h = gc >> 2;
        y_t[(((size_t)(b * 4 + f)) * 1024 + l) * 512 + h] = (_Float16)c;
      }
}

// ---- K2: S[b,i,j] = max_f sum_h Y_f[i,h] Y_f[j,h] ----
// 512 blocks 1D, b = id & 7 (XCD pin, fetch-ideal since r3). Pointers bump
// +64/step; at f-boundary += PLANE-512 to land on next plane's tile 0.

__global__ __launch_bounds__(256) void score_kernel(const _Float16* __restrict__ y_t,
                                                    float* __restrict__ S) {
  __shared__ __align__(16) _Float16 ldsA[2][128 * 64];
  __shared__ __align__(16) _Float16 ldsB[2][128 * 64];
  int id = blockIdx.x;
  int b = id & 7;
  int tile = id >> 3;          // 0..63
  int i0 = (tile >> 3) * 128, j0 = (tile & 7) * 128;
  int t = threadIdx.x, lane = t & 63, w = t >> 6;
  int wm = w >> 1, wn = w & 1, quad = lane >> 4, l16 = lane & 15;
  int lofs = t * 8;
  const int PLANE = 1024 * 512;
  const _Float16* base = y_t + (size_t)b * 4 * PLANE;
  const _Float16* gpA[4]; const _Float16* gpB[4];
  init_stage_ptrs(base, i0, 512, gpA);
  init_stage_ptrs(base, j0, 512, gpB);
  floatx4 acc[4][4], smax[4][4];
  ZERO_ACC(acc);
  stage4(gpA, ldsA[0], lofs); bump(gpA, 64);
  stage4(gpB, ldsB[0], lofs); bump(gpB, 64);
#pragma unroll 1
  for (int f = 0; f < 4; ++f) {
#pragma unroll 1
    for (int kt = 0; kt < 8; ++kt) {
      __syncthreads();
      if (f * 8 + kt < 31) {
        if (kt == 7) { bump(gpA, PLANE - 512); bump(gpB, PLANE - 512); }
        stage4(gpA, ldsA[(kt + 1) & 1], lofs); bump(gpA, 64);
        stage4(gpB, ldsB[(kt + 1) & 1], lofs); bump(gpB, 64);
      }
      mfma_tile(ldsA[kt & 1], ldsB[kt & 1], acc, wm, wn, l16, quad);
    }
    if (f == 0) {
#pragma unroll
      for (int mi = 0; mi < 4; ++mi)
#pragma unroll
        for (int ni = 0; ni < 4; ++ni) smax[mi][ni] = acc[mi][ni];
    } else {
#pragma unroll
      for (int mi = 0; mi < 4; ++mi)
#pragma unroll
        for (int ni = 0; ni < 4; ++ni)
#pragma unroll
          for (int r = 0; r < 4; ++r)
            smax[mi][ni][r] = fmaxf(smax[mi][ni][r], acc[mi][ni][r]);
    }
    ZERO_ACC(acc);
  }
  float* Sb = S + (size_t)b * 1024 * 1024;
#pragma unroll
  for (int mi = 0; mi < 4; ++mi)
#pragma unroll
    for (int ni = 0; ni < 4; ++ni)
#pragma unroll
      for (int r = 0; r < 4; ++r) {
        int gi = i0 + wm * 64 + mi * 16 + quad * 4 + r;
        int gj = j0 + wn * 64 + ni * 16 + l16;
        Sb[(size_t)gi * 1024 + gj] = smax[mi][ni][r];
      }
}

// ---- K3: allennlp masked softmax per row -> alpha fp16 ----
// p = softmax(logits*m) (masked entries participate as 0), alpha = p*m/(sum(p*m)+1e-13)

__global__ __launch_bounds__(256) void softmax_kernel(const float* __restrict__ S,
                                                      const int* __restrict__ xmask,
                                                      _Float16* __restrict__ alpha) {
  __shared__ float red[16];
  int row = blockIdx.x;               // 0..8191
  int b = row >> 10, l = row & 1023;
  const float* sr = S + (size_t)row * 1024;
  const int* mr = xmask + b * 1024;
  int t = threadIdx.x, lane = t & 63, wid = t >> 6;
  int rm = mr[l];
  float v[4], mm[4];
  float vmax = 0.0f;  // masked entries are exactly 0, so max >= 0 always
#pragma unroll
  for (int q = 0; q < 4; ++q) {
    int i = t + q * 256;
    int m = (rm && mr[i] && (i != l)) ? 1 : 0;
    mm[q] = (float)m;
    v[q] = m ? sr[i] : 0.0f;
    vmax = fmaxf(vmax, v[q]);
  }
  for (int off = 32; off; off >>= 1) vmax = fmaxf(vmax, __shfl_down(vmax, off));
  if (lane == 0) red[wid] = vmax;
  __syncthreads();
  if (t == 0) red[8] = fmaxf(fmaxf(red[0], red[1]), fmaxf(red[2], red[3]));
  __syncthreads();
  vmax = red[8];
  float e[4], E = 0.0f, E2 = 0.0f;
#pragma unroll
  for (int q = 0; q < 4; ++q) {
    e[q] = expf(v[q] - vmax);
    E += e[q];
    E2 += e[q] * mm[q];
  }
  for (int off = 32; off; off >>= 1) {
    E += __shfl_down(E, off);
    E2 += __shfl_down(E2, off);
  }
  if (lane == 0) { red[wid] = E; red[4 + wid] = E2; }
  __syncthreads();
  if (t == 0) {
    red[9] = red[0] + red[1] + red[2] + red[3];
    red[10] = red[4] + red[5] + red[6] + red[7];
  }
  __syncthreads();
  E = red[9]; E2 = red[10];
  // alpha_i = (e_i/E)*m_i / (E2/E + 1e-13) = e_i*m_i / (E2 + 1e-13*E)
  float inv = 1.0f / (E2 + 1e-13f * E);
  _Float16* ar = alpha + (size_t)row * 1024;
#pragma unroll
  for (int q = 0; q < 4; ++q) {
    int i = t + q * 256;
    ar[i] = (_Float16)(e[q] * mm[q] * inv);
  }
}

// ---- K4: enc[b] = alpha[b] @ x[b]  (uses xT (B,H,L) as B-operand) ----
// 1D grid of 256, b = id & 7 (XCD pin; per-batch alpha(2MB)+xT(1MB) fits L2)

__global__ __launch_bounds__(256) void attn_kernel(const _Float16* __restrict__ alpha,
                                                   const _Float16* __restrict__ xT,
                                                   _Float16* __restrict__ enc) {
  __shared__ __align__(16) _Float16 ldsA[2][128 * 64];
  __shared__ __align__(16) _Float16 ldsB[2][128 * 64];
  int id = blockIdx.x;
  int b = id & 7;
  int tile = id >> 3;               // 0..31
  int i0 = (tile >> 2) * 128;       // 8 i-tiles
  int n0 = (tile & 3) * 128;        // 4 n-tiles
  const _Float16* A = alpha + (size_t)b * 1024 * 1024;
  const _Float16* Bm = xT + (size_t)b * 512 * 1024;
  int t = threadIdx.x, lane = t & 63, w = t >> 6;
  int wm = w >> 1, wn = w & 1, quad = lane >> 4, l16 = lane & 15;
  int lofs = t * 8;
  const _Float16* gpA[4]; const _Float16* gpB[4];
  init_stage_ptrs(A, i0, 1024, gpA);
  init_stage_ptrs(Bm, n0, 1024, gpB);
  floatx4 acc[4][4];
  ZERO_ACC(acc);
  stage4(gpA, ldsA[0], lofs); bump(gpA, 64);
  stage4(gpB, ldsB[0], lofs); bump(gpB, 64);
#pragma unroll 1
  for (int kt = 0; kt < 16; ++kt) {
    __syncthreads();
    if (kt < 15) {
      stage4(gpA, ldsA[(kt + 1) & 1], lofs); bump(gpA, 64);
      stage4(gpB, ldsB[(kt + 1) & 1], lofs); bump(gpB, 64);
    }
    mfma_tile(ldsA[kt & 1], ldsB[kt & 1], acc, wm, wn, l16, quad);
  }
  _Float16* eb = enc + (size_t)b * 1024 * 512;
#pragma unroll
  for (int mi = 0; mi < 4; ++mi)
#pragma unroll
    for (int ni = 0; ni < 4; ++ni)
#pragma unroll
      for (int r = 0; r < 4; ++r) {
        int gr = i0 + wm * 64 + mi * 16 + quad * 4 + r;  // l
        int gc = n0 + wn * 64 + ni * 16 + l16;           // h
        eb[(size_t)gr * 512 + gc] = (_Float16)acc[mi][ni][r];
      }
}

// ---- K5: gate = sigmoid([x|enc] @ W_gate + b_gate); out = gate*[x16|enc] ----
// grid (64, 8): i0 on x so XCD k caches only its A-tiles + all of B (2 MB)

__global__ __launch_bounds__(256) void gate_kernel(const _Float16* __restrict__ x16,
                                                   const _Float16* __restrict__ enc,
                                                   const _Float16* __restrict__ WgT,
                                                   const float* __restrict__ bg,
                                                   float* __restrict__ out) {
  __shared__ __align__(16) _Float16 ldsA[2][128 * 64];
  __shared__ __align__(16) _Float16 ldsB[2][128 * 64];
  int i0 = blockIdx.x * 128, n0 = blockIdx.y * 128;
  int t = threadIdx.x, lane = t & 63, w = t >> 6;
  int wm = w >> 1, wn = w & 1, quad = lane >> 4, l16 = lane & 15;
  int lofs = t * 8;
  const _Float16* gpA[4]; const _Float16* gpA2[4]; const _Float16* gpB[4];
  init_stage_ptrs(x16, i0, 512, gpA);
  init_stage_ptrs(enc, i0, 512, gpA2);
  init_stage_ptrs(WgT, n0, 1024, gpB);
  floatx4 acc[4][4];
  ZERO_ACC(acc);
  stage4(gpA, ldsA[0], lofs); bump(gpA, 64);
  stage4(gpB, ldsB[0], lofs); bump(gpB, 64);
  // A prefetch for step kt+1: kt<7 -> x16 tile kt+1; kt=7..14 -> enc tile kt-7.
#pragma unroll 1
  for (int kt = 0; kt < 16; ++kt) {
    __syncthreads();
    if (kt < 15) {
      if (kt < 7) { stage4(gpA,  ldsA[(kt + 1) & 1], lofs); bump(gpA, 64); }
      else        { stage4(gpA2, ldsA[(kt + 1) & 1], lofs); bump(gpA2, 64); }
      stage4(gpB, ldsB[(kt + 1) & 1], lofs); bump(gpB, 64);
    }
    mfma_tile(ldsA[kt & 1], ldsB[kt & 1], acc, wm, wn, l16, quad);
  }
#pragma unroll
  for (int mi = 0; mi < 4; ++mi)
#pragma unroll
    for (int ni = 0; ni < 4; ++ni)
#pragma unroll
      for (int r = 0; r < 4; ++r) {
        int gr = i0 + wm * 64 + mi * 16 + quad * 4 + r;  // 0..8191
        int gc = n0 + wn * 64 + ni * 16 + l16;           // 0..1023
        float c = acc[mi][ni][r] + bg[gc];
        float g = 1.0f / (1.0f + expf(-c));
        float jv = (gc < 512) ? (float)x16[(size_t)gr * 512 + gc]
                              : (float)enc[(size_t)gr * 512 + (gc - 512)];
        out[(size_t)gr * 1024 + gc] = g * jv;
      }
}

// ---- launch ----

extern "C" void kernel_launch(void* const* d_in, const int* in_sizes, int n_in,
                              void* d_out, int out_size, void* d_ws, size_t ws_size,
                              hipStream_t stream) {
  const float* x  = (const float*)d_in[0];   // (8,1024,512)
  const int* xm   = (const int*)d_in[1];     // (8,1024)
  const float* Wp = (const float*)d_in[2];   // (512,2048)
  const float* bp = (const float*)d_in[3];   // (2048)
  const float* Wg = (const float*)d_in[4];   // (1024,1024)
  const float* bg = (const float*)d_in[5];   // (1024)
  float* out = (float*)d_out;

  char* ws = (char*)d_ws;
  const size_t MB = 1024 * 1024;
  _Float16* x16 = (_Float16*)(ws);            // 8 MB  (8192,512)
  _Float16* xT  = (_Float16*)(ws + 8 * MB);   // 8 MB  (8,512,1024)
  _Float16* WpT = (_Float16*)(ws + 16 * MB);  // 2 MB  (2048,512)
  _Float16* WgT = (_Float16*)(ws + 18 * MB);  // 2 MB  (1024,1024)
  _Float16* y_t = (_Float16*)(ws + 20 * MB);  // 32 MB (8,4,1024,512)
  float*    S   = (float*)(ws + 52 * MB);     // 32 MB (8,1024,1024)  [end: 84 MB]
  // y_t is dead after score_kernel: alias alpha/enc onto it
  _Float16* alpha = (_Float16*)(ws + 20 * MB); // 16 MB (8,1024,1024)
  _Float16* enc   = (_Float16*)(ws + 36 * MB); // 8 MB  (8,1024,512)

  cast_kernel<<<4096, 256, 0, stream>>>(x, x16);
  transpose_cast_kernel<<<dim3(16, 32, 8), 256, 0, stream>>>(x, xT, 1024, 512);
  transpose_cast_kernel<<<dim3(64, 16, 1), 256, 0, stream>>>(Wp, WpT, 512, 2048);
  transpose_cast_kernel<<<dim3(32, 32, 1), 256, 0, stream>>>(Wg, WgT, 1024, 1024);

  proj_kernel<<<dim3(64, 16), 256, 0, stream>>>(x16, WpT, bp, y_t);
  score_kernel<<<512, 256, 0, stream>>>(y_t, S);
  softmax_kernel<<<8192, 256, 0, stream>>>(S, xm, alpha);
  attn_kernel<<<256, 256, 0, stream>>>(alpha, xT, enc);
  gate_kernel<<<dim3(64, 8), 256, 0, stream>>>(x16, enc, WgT, bg, out);
}

// Round 7
// 220.124 us; speedup vs baseline: 1.2840x; 1.1699x over previous
//
#include <hip/hip_runtime.h>

// Problem constants: B=8, L=1024, H=512, F=4
// out = gate * [x | alpha @ x],  gate = sigmoid([x|enc] @ W_gate)
// alpha = masked_softmax(max_f(Y_f Y_f^T)),  Y = relu(x @ W_proj)
//
// Round 7: score -> 512-thread blocks (8 waves, 2x4 wave grid) = 16 waves/CU
// (was 8): barrier-drain latency is the residual (r6: MfmaUtil 17%, VALU 16%,
// HBM 11% -- all idle); waves are the only latency-hiding resource left.
// attn -> 64-row i-tiles (grid 512, 2 blk/CU). Pre-pass merged 4->2 launches.

typedef _Float16 half8 __attribute__((ext_vector_type(8)));
typedef _Float16 half4 __attribute__((ext_vector_type(4)));
typedef float floatx4 __attribute__((ext_vector_type(4)));

typedef const __attribute__((address_space(1))) void* gas_ptr;
typedef __attribute__((address_space(3))) void* las_ptr;

// ---- staging machinery ----
// LDS tile layout: row-major [rows][64] fp16, 16B groups XOR-swizzled by
// (row&7). Chunk c covers row=c>>3, group kg=c&7, global col (kg^(row&7))*8;
// LDS dst = c*16 B (wave-uniform base + lane*16 contract of global_load_lds).
// NCH chunks per thread, NT threads: rows = NCH*NT/8.

template<int NCH, int NT>
__device__ __forceinline__ void init_ptrs(const _Float16* src, int row0, int ld,
                                          const _Float16* gp[NCH]) {
  int t = threadIdx.x;
#pragma unroll
  for (int p = 0; p < NCH; ++p) {
    int c = p * NT + t;
    int row = c >> 3;
    int kg = c & 7;
    int gk = (kg ^ (row & 7)) << 3;
    gp[p] = src + (size_t)(row0 + row) * ld + gk;
  }
}

template<int NCH, int NT>
__device__ __forceinline__ void stage(const _Float16* const gp[NCH], _Float16* ldsbuf) {
  int t = threadIdx.x;
#pragma unroll
  for (int p = 0; p < NCH; ++p)
    __builtin_amdgcn_global_load_lds((gas_ptr)gp[p],
                                     (las_ptr)(ldsbuf + t * 8 + p * NT * 8), 16, 0, 0);
}

template<int NCH>
__device__ __forceinline__ void bump(const _Float16* gp[NCH], int d) {
#pragma unroll
  for (int p = 0; p < NCH; ++p) gp[p] += d;
}

__device__ __forceinline__ half8 frag_ld(const _Float16* lds, int row, int g) {
  return *(const half8*)(lds + row * 64 + ((g ^ (row & 7)) << 3));
}

// ---- pre-pass ----

// x (8,1024,512) fp32 -> x16 (straight fp16) + xT (8,512,1024) fp16
__global__ void x_prep_kernel(const float* __restrict__ in, _Float16* __restrict__ x16,
                              _Float16* __restrict__ xT) {
  __shared__ float tile[32][33];
  const int R = 1024, C = 512;
  int c0 = blockIdx.x * 32, r0 = blockIdx.y * 32;
  size_t boff = (size_t)blockIdx.z * R * C;
  in += boff; x16 += boff; xT += boff;
  int tx = threadIdx.x & 31, ty = threadIdx.x >> 5;  // 32 x 8
#pragma unroll
  for (int i = 0; i < 32; i += 8) {
    float v = in[(size_t)(r0 + ty + i) * C + c0 + tx];
    tile[ty + i][tx] = v;
    x16[(size_t)(r0 + ty + i) * C + c0 + tx] = (_Float16)v;
  }
  __syncthreads();
#pragma unroll
  for (int i = 0; i < 32; i += 8)
    xT[(size_t)(c0 + ty + i) * R + r0 + tx] = (_Float16)tile[tx][ty + i];
}

// z=0: Wp (512,2048)->WpT(2048,512); z=1: Wg (1024,1024)->WgT(1024,1024)
__global__ void w_prep_kernel(const float* __restrict__ Wp, _Float16* __restrict__ WpT,
                              const float* __restrict__ Wg, _Float16* __restrict__ WgT) {
  __shared__ float tile[32][33];
  const float* in; _Float16* out; int R, C, c0, r0;
  if (blockIdx.z == 0) {
    in = Wp; out = WpT; R = 512; C = 2048;
    c0 = blockIdx.x * 32; r0 = blockIdx.y * 32;
  } else {
    in = Wg; out = WgT; R = 1024; C = 1024;
    c0 = (blockIdx.x & 31) * 32; r0 = (blockIdx.y * 2 + (blockIdx.x >> 5)) * 32;
  }
  int tx = threadIdx.x & 31, ty = threadIdx.x >> 5;
#pragma unroll
  for (int i = 0; i < 32; i += 8)
    tile[ty + i][tx] = in[(size_t)(r0 + ty + i) * C + c0 + tx];
  __syncthreads();
#pragma unroll
  for (int i = 0; i < 32; i += 8)
    out[(size_t)(c0 + ty + i) * R + r0 + tx] = (_Float16)tile[tx][ty + i];
}

// ---- K1: y = relu(x @ W_proj + b_proj) -> y_t (B,F,L,H) fp16 ----
// 256 thr, 2x2 waves, 128x128 tile, dbuf BK=64 (r6 structure, unchanged)

__device__ __forceinline__ void mfma_tile44(const _Float16* lds_a, const _Float16* lds_b,
                                            floatx4 acc[4][4], int wm, int wn,
                                            int l16, int quad) {
#pragma unroll
  for (int kf = 0; kf < 2; ++kf) {
    half8 af[4], bf[4];
#pragma unroll
    for (int i = 0; i < 4; ++i) af[i] = frag_ld(lds_a, wm * 64 + i * 16 + l16, kf * 4 + quad);
#pragma unroll
    for (int i = 0; i < 4; ++i) bf[i] = frag_ld(lds_b, wn * 64 + i * 16 + l16, kf * 4 + quad);
#pragma unroll
    for (int mi = 0; mi < 4; ++mi)
#pragma unroll
      for (int ni = 0; ni < 4; ++ni)
        acc[mi][ni] = __builtin_amdgcn_mfma_f32_16x16x32_f16(af[mi], bf[ni], acc[mi][ni], 0, 0, 0);
  }
}

#define ZERO_ACC44(acc)                                 \
  _Pragma("unroll") for (int mi = 0; mi < 4; ++mi)      \
  _Pragma("unroll") for (int ni = 0; ni < 4; ++ni)      \
  _Pragma("unroll") for (int r = 0; r < 4; ++r) acc[mi][ni][r] = 0.0f;

__global__ __launch_bounds__(256) void proj_kernel(const _Float16* __restrict__ x16,
                                                   const _Float16* __restrict__ WpT,
                                                   const float* __restrict__ bp,
                                                   _Float16* __restrict__ y_t) {
  __shared__ __align__(16) _Float16 ldsA[2][128 * 64];
  __shared__ __align__(16) _Float16 ldsB[2][128 * 64];
  int i0 = blockIdx.x * 128, n0 = blockIdx.y * 128;
  int t = threadIdx.x, lane = t & 63, w = t >> 6;
  int wm = w >> 1, wn = w & 1, quad = lane >> 4, l16 = lane & 15;
  const _Float16* gpA[4]; const _Float16* gpB[4];
  init_ptrs<4, 256>(x16, i0, 512, gpA);
  init_ptrs<4, 256>(WpT, n0, 512, gpB);
  floatx4 acc[4][4];
  ZERO_ACC44(acc);
  stage<4, 256>(gpA, ldsA[0]); bump<4>(gpA, 64);
  stage<4, 256>(gpB, ldsB[0]); bump<4>(gpB, 64);
#pragma unroll 1
  for (int kt = 0; kt < 8; ++kt) {
    __syncthreads();
    if (kt < 7) {
      stage<4, 256>(gpA, ldsA[(kt + 1) & 1]); bump<4>(gpA, 64);
      stage<4, 256>(gpB, ldsB[(kt + 1) & 1]); bump<4>(gpB, 64);
    }
    mfma_tile44(ldsA[kt & 1], ldsB[kt & 1], acc, wm, wn, l16, quad);
  }
#pragma unroll
  for (int mi = 0; mi < 4; ++mi)
#pragma unroll
    for (int ni = 0; ni < 4; ++ni)
#pragma unroll
      for (int r = 0; r < 4; ++r) {
        int gr = i0 + wm * 64 + mi * 16 + quad * 4 + r;   // 0..8191
        int gc = n0 + wn * 64 + ni * 16 + l16;            // 0..2047
        float c = fmaxf(acc[mi][ni][r] + bp[gc], 0.0f);
        int b = gr >> 10, l = gr & 1023;
        int f = gc & 3, h = gc >> 2;
        y_t[(((size_t)(b * 4 + f)) * 1024 + l) * 512 + h] = (_Float16)c;
      }
}

// ---- K2: S[b,i,j] = max_f sum_h Y_f[i,h] Y_f[j,h] ----
// 512 blocks x 512 threads (8 waves, 2x4 wave grid, wave tile 64x32).
// 2 blocks/CU (LDS 64KB) = 16 waves/CU. b = id & 7 XCD pin (fetch-ideal).

__global__ __launch_bounds__(512, 4) void score_kernel(const _Float16* __restrict__ y_t,
                                                       float* __restrict__ S) {
  __shared__ __align__(16) _Float16 ldsA[2][128 * 64];
  __shared__ __align__(16) _Float16 ldsB[2][128 * 64];
  int id = blockIdx.x;
  int b = id & 7;
  int tile = id >> 3;          // 0..63
  int i0 = (tile >> 3) * 128, j0 = (tile & 7) * 128;
  int t = threadIdx.x, lane = t & 63, w = t >> 6;      // w 0..7
  int wm = w >> 2, wn = w & 3, quad = lane >> 4, l16 = lane & 15;
  const int PLANE = 1024 * 512;
  const _Float16* base = y_t + (size_t)b * 4 * PLANE;
  const _Float16* gpA[2]; const _Float16* gpB[2];
  init_ptrs<2, 512>(base, i0, 512, gpA);
  init_ptrs<2, 512>(base, j0, 512, gpB);
  floatx4 acc[4][2], smax[4][2];
#pragma unroll
  for (int mi = 0; mi < 4; ++mi)
#pragma unroll
    for (int ni = 0; ni < 2; ++ni)
#pragma unroll
      for (int r = 0; r < 4; ++r) acc[mi][ni][r] = 0.0f;
  stage<2, 512>(gpA, ldsA[0]); bump<2>(gpA, 64);
  stage<2, 512>(gpB, ldsB[0]); bump<2>(gpB, 64);
#pragma unroll 1
  for (int f = 0; f < 4; ++f) {
#pragma unroll 1
    for (int kt = 0; kt < 8; ++kt) {
      __syncthreads();
      if (f * 8 + kt < 31) {
        if (kt == 7) { bump<2>(gpA, PLANE - 512); bump<2>(gpB, PLANE - 512); }
        stage<2, 512>(gpA, ldsA[(kt + 1) & 1]); bump<2>(gpA, 64);
        stage<2, 512>(gpB, ldsB[(kt + 1) & 1]); bump<2>(gpB, 64);
      }
      const _Float16* la = ldsA[kt & 1];
      const _Float16* lb = ldsB[kt & 1];
#pragma unroll
      for (int kf = 0; kf < 2; ++kf) {
        half8 af[4], bf[2];
#pragma unroll
        for (int i = 0; i < 4; ++i) af[i] = frag_ld(la, wm * 64 + i * 16 + l16, kf * 4 + quad);
#pragma unroll
        for (int i = 0; i < 2; ++i) bf[i] = frag_ld(lb, wn * 32 + i * 16 + l16, kf * 4 + quad);
#pragma unroll
        for (int mi = 0; mi < 4; ++mi)
#pragma unroll
          for (int ni = 0; ni < 2; ++ni)
            acc[mi][ni] = __builtin_amdgcn_mfma_f32_16x16x32_f16(af[mi], bf[ni], acc[mi][ni], 0, 0, 0);
      }
    }
    if (f == 0) {
#pragma unroll
      for (int mi = 0; mi < 4; ++mi)
#pragma unroll
        for (int ni = 0; ni < 2; ++ni) smax[mi][ni] = acc[mi][ni];
    } else {
#pragma unroll
      for (int mi = 0; mi < 4; ++mi)
#pragma unroll
        for (int ni = 0; ni < 2; ++ni)
#pragma unroll
          for (int r = 0; r < 4; ++r)
            smax[mi][ni][r] = fmaxf(smax[mi][ni][r], acc[mi][ni][r]);
    }
#pragma unroll
    for (int mi = 0; mi < 4; ++mi)
#pragma unroll
      for (int ni = 0; ni < 2; ++ni)
#pragma unroll
        for (int r = 0; r < 4; ++r) acc[mi][ni][r] = 0.0f;
  }
  float* Sb = S + (size_t)b * 1024 * 1024;
#pragma unroll
  for (int mi = 0; mi < 4; ++mi)
#pragma unroll
    for (int ni = 0; ni < 2; ++ni)
#pragma unroll
      for (int r = 0; r < 4; ++r) {
        int gi = i0 + wm * 64 + mi * 16 + quad * 4 + r;
        int gj = j0 + wn * 32 + ni * 16 + l16;
        Sb[(size_t)gi * 1024 + gj] = smax[mi][ni][r];
      }
}

// ---- K3: allennlp masked softmax per row -> alpha fp16 ----
// p = softmax(logits*m) (masked entries participate as 0), alpha = p*m/(sum(p*m)+1e-13)

__global__ __launch_bounds__(256) void softmax_kernel(const float* __restrict__ S,
                                                      const int* __restrict__ xmask,
                                                      _Float16* __restrict__ alpha) {
  __shared__ float red[16];
  int row = blockIdx.x;               // 0..8191
  int b = row >> 10, l = row & 1023;
  const float* sr = S + (size_t)row * 1024;
  const int* mr = xmask + b * 1024;
  int t = threadIdx.x, lane = t & 63, wid = t >> 6;
  int rm = mr[l];
  float v[4], mm[4];
  float vmax = 0.0f;  // masked entries are exactly 0, so max >= 0 always
#pragma unroll
  for (int q = 0; q < 4; ++q) {
    int i = t + q * 256;
    int m = (rm && mr[i] && (i != l)) ? 1 : 0;
    mm[q] = (float)m;
    v[q] = m ? sr[i] : 0.0f;
    vmax = fmaxf(vmax, v[q]);
  }
  for (int off = 32; off; off >>= 1) vmax = fmaxf(vmax, __shfl_down(vmax, off));
  if (lane == 0) red[wid] = vmax;
  __syncthreads();
  if (t == 0) red[8] = fmaxf(fmaxf(red[0], red[1]), fmaxf(red[2], red[3]));
  __syncthreads();
  vmax = red[8];
  float e[4], E = 0.0f, E2 = 0.0f;
#pragma unroll
  for (int q = 0; q < 4; ++q) {
    e[q] = expf(v[q] - vmax);
    E += e[q];
    E2 += e[q] * mm[q];
  }
  for (int off = 32; off; off >>= 1) {
    E += __shfl_down(E, off);
    E2 += __shfl_down(E2, off);
  }
  if (lane == 0) { red[wid] = E; red[4 + wid] = E2; }
  __syncthreads();
  if (t == 0) {
    red[9] = red[0] + red[1] + red[2] + red[3];
    red[10] = red[4] + red[5] + red[6] + red[7];
  }
  __syncthreads();
  E = red[9]; E2 = red[10];
  float inv = 1.0f / (E2 + 1e-13f * E);
  _Float16* ar = alpha + (size_t)row * 1024;
#pragma unroll
  for (int q = 0; q < 4; ++q) {
    int i = t + q * 256;
    ar[i] = (_Float16)(e[q] * mm[q] * inv);
  }
}

// ---- K4: enc[b] = alpha[b] @ x[b]  (xT (B,H,L) as B-operand) ----
// 512 blocks x 256 thr: 64-row i-tiles (16) x 4 n-tiles x 8 b. LDS 48 KB ->
// 2 blocks/CU co-resident (8 waves/CU, was 4). Wave grid 1x4, tile 64x32.

__global__ __launch_bounds__(256) void attn_kernel(const _Float16* __restrict__ alpha,
                                                   const _Float16* __restrict__ xT,
                                                   _Float16* __restrict__ enc) {
  __shared__ __align__(16) _Float16 ldsA[2][64 * 64];
  __shared__ __align__(16) _Float16 ldsB[2][128 * 64];
  int id = blockIdx.x;
  int b = id & 7;
  int r2 = id >> 3;                 // 0..63
  int i0 = (r2 >> 2) * 64;          // 16 i-tiles of 64
  int n0 = (r2 & 3) * 128;          // 4 n-tiles of 128
  const _Float16* A = alpha + (size_t)b * 1024 * 1024;
  const _Float16* Bm = xT + (size_t)b * 512 * 1024;
  int t = threadIdx.x, lane = t & 63, wn = t >> 6;   // wave grid 1x4
  int quad = lane >> 4, l16 = lane & 15;
  const _Float16* gpA[2]; const _Float16* gpB[4];
  init_ptrs<2, 256>(A, i0, 1024, gpA);
  init_ptrs<4, 256>(Bm, n0, 1024, gpB);
  floatx4 acc[4][2];
#pragma unroll
  for (int mi = 0; mi < 4; ++mi)
#pragma unroll
    for (int ni = 0; ni < 2; ++ni)
#pragma unroll
      for (int r = 0; r < 4; ++r) acc[mi][ni][r] = 0.0f;
  stage<2, 256>(gpA, ldsA[0]); bump<2>(gpA, 64);
  stage<4, 256>(gpB, ldsB[0]); bump<4>(gpB, 64);
#pragma unroll 1
  for (int kt = 0; kt < 16; ++kt) {
    __syncthreads();
    if (kt < 15) {
      stage<2, 256>(gpA, ldsA[(kt + 1) & 1]); bump<2>(gpA, 64);
      stage<4, 256>(gpB, ldsB[(kt + 1) & 1]); bump<4>(gpB, 64);
    }
    const _Float16* la = ldsA[kt & 1];
    const _Float16* lb = ldsB[kt & 1];
#pragma unroll
    for (int kf = 0; kf < 2; ++kf) {
      half8 af[4], bf[2];
#pragma unroll
      for (int i = 0; i < 4; ++i) af[i] = frag_ld(la, i * 16 + l16, kf * 4 + quad);
#pragma unroll
      for (int i = 0; i < 2; ++i) bf[i] = frag_ld(lb, wn * 32 + i * 16 + l16, kf * 4 + quad);
#pragma unroll
      for (int mi = 0; mi < 4; ++mi)
#pragma unroll
        for (int ni = 0; ni < 2; ++ni)
          acc[mi][ni] = __builtin_amdgcn_mfma_f32_16x16x32_f16(af[mi], bf[ni], acc[mi][ni], 0, 0, 0);
    }
  }
  _Float16* eb = enc + (size_t)b * 1024 * 512;
#pragma unroll
  for (int mi = 0; mi < 4; ++mi)
#pragma unroll
    for (int ni = 0; ni < 2; ++ni)
#pragma unroll
      for (int r = 0; r < 4; ++r) {
        int gr = i0 + mi * 16 + quad * 4 + r;            // l
        int gc = n0 + wn * 32 + ni * 16 + l16;           // h
        eb[(size_t)gr * 512 + gc] = (_Float16)acc[mi][ni][r];
      }
}

// ---- K5: gate = sigmoid([x|enc] @ W_gate + b_gate); out = gate*[x16|enc] ----
// grid (64, 8): i0 on x so XCD k caches only its A-tiles + all of B (2 MB)

__global__ __launch_bounds__(256) void gate_kernel(const _Float16* __restrict__ x16,
                                                   const _Float16* __restrict__ enc,
                                                   const _Float16* __restrict__ WgT,
                                                   const float* __restrict__ bg,
                                                   float* __restrict__ out) {
  __shared__ __align__(16) _Float16 ldsA[2][128 * 64];
  __shared__ __align__(16) _Float16 ldsB[2][128 * 64];
  int i0 = blockIdx.x * 128, n0 = blockIdx.y * 128;
  int t = threadIdx.x, lane = t & 63, w = t >> 6;
  int wm = w >> 1, wn = w & 1, quad = lane >> 4, l16 = lane & 15;
  const _Float16* gpA[4]; const _Float16* gpA2[4]; const _Float16* gpB[4];
  init_ptrs<4, 256>(x16, i0, 512, gpA);
  init_ptrs<4, 256>(enc, i0, 512, gpA2);
  init_ptrs<4, 256>(WgT, n0, 1024, gpB);
  floatx4 acc[4][4];
  ZERO_ACC44(acc);
  stage<4, 256>(gpA, ldsA[0]); bump<4>(gpA, 64);
  stage<4, 256>(gpB, ldsB[0]); bump<4>(gpB, 64);
#pragma unroll 1
  for (int kt = 0; kt < 16; ++kt) {
    __syncthreads();
    if (kt < 15) {
      if (kt < 7) { stage<4, 256>(gpA,  ldsA[(kt + 1) & 1]); bump<4>(gpA, 64); }
      else        { stage<4, 256>(gpA2, ldsA[(kt + 1) & 1]); bump<4>(gpA2, 64); }
      stage<4, 256>(gpB, ldsB[(kt + 1) & 1]); bump<4>(gpB, 64);
    }
    mfma_tile44(ldsA[kt & 1], ldsB[kt & 1], acc, wm, wn, l16, quad);
  }
#pragma unroll
  for (int mi = 0; mi < 4; ++mi)
#pragma unroll
    for (int ni = 0; ni < 4; ++ni)
#pragma unroll
      for (int r = 0; r < 4; ++r) {
        int gr = i0 + wm * 64 + mi * 16 + quad * 4 + r;  // 0..8191
        int gc = n0 + wn * 64 + ni * 16 + l16;           // 0..1023
        float c = acc[mi][ni][r] + bg[gc];
        float g = 1.0f / (1.0f + expf(-c));
        float jv = (gc < 512) ? (float)x16[(size_t)gr * 512 + gc]
                              : (float)enc[(size_t)gr * 512 + (gc - 512)];
        out[(size_t)gr * 1024 + gc] = g * jv;
      }
}

// ---- launch ----

extern "C" void kernel_launch(void* const* d_in, const int* in_sizes, int n_in,
                              void* d_out, int out_size, void* d_ws, size_t ws_size,
                              hipStream_t stream) {
  const float* x  = (const float*)d_in[0];   // (8,1024,512)
  const int* xm   = (const int*)d_in[1];     // (8,1024)
  const float* Wp = (const float*)d_in[2];   // (512,2048)
  const float* bp = (const float*)d_in[3];   // (2048)
  const float* Wg = (const float*)d_in[4];   // (1024,1024)
  const float* bg = (const float*)d_in[5];   // (1024)
  float* out = (float*)d_out;

  char* ws = (char*)d_ws;
  const size_t MB = 1024 * 1024;
  _Float16* x16 = (_Float16*)(ws);            // 8 MB  (8192,512)
  _Float16* xT  = (_Float16*)(ws + 8 * MB);   // 8 MB  (8,512,1024)
  _Float16* WpT = (_Float16*)(ws + 16 * MB);  // 2 MB  (2048,512)
  _Float16* WgT = (_Float16*)(ws + 18 * MB);  // 2 MB  (1024,1024)
  _Float16* y_t = (_Float16*)(ws + 20 * MB);  // 32 MB (8,4,1024,512)
  float*    S   = (float*)(ws + 52 * MB);     // 32 MB (8,1024,1024)  [end: 84 MB]
  // y_t is dead after score_kernel: alias alpha/enc onto it
  _Float16* alpha = (_Float16*)(ws + 20 * MB); // 16 MB (8,1024,1024)
  _Float16* enc   = (_Float16*)(ws + 36 * MB); // 8 MB  (8,1024,512)

  x_prep_kernel<<<dim3(16, 32, 8), 256, 0, stream>>>(x, x16, xT);
  w_prep_kernel<<<dim3(64, 16, 2), 256, 0, stream>>>(Wp, WpT, Wg, WgT);

  proj_kernel<<<dim3(64, 16), 256, 0, stream>>>(x16, WpT, bp, y_t);
  score_kernel<<<512, 512, 0, stream>>>(y_t, S);
  softmax_kernel<<<8192, 256, 0, stream>>>(S, xm, alpha);
  attn_kernel<<<512, 256, 0, stream>>>(alpha, xT, enc);
  gate_kernel<<<dim3(64, 8), 256, 0, stream>>>(x16, enc, WgT, bg, out);
}

// Round 9
// 217.225 us; speedup vs baseline: 1.3012x; 1.0133x over previous
//
#include <hip/hip_runtime.h>

// Problem constants: B=8, L=1024, H=512, F=4
// out = gate * [x | alpha @ x],  gate = sigmoid([x|enc] @ W_gate)
// alpha = masked_softmax(max_f(Y_f Y_f^T)),  Y = relu(x @ W_proj)
//
// Round 9: r8 design with the compile fix -- no ARRAYS of pointers into LDS
// (clang emits an unloadable addrspacecast static initializer); scalar LDS
// pointers + ternary select instead. Score exploits S symmetry (36/64 tiles,
// mirror via LDS transpose); proj/gate on the 512-thread 8-wave structure.

typedef _Float16 half8 __attribute__((ext_vector_type(8)));
typedef float floatx4 __attribute__((ext_vector_type(4)));

typedef const __attribute__((address_space(1))) void* gas_ptr;
typedef __attribute__((address_space(3))) void* las_ptr;

// ---- staging machinery ----
// LDS tile layout: row-major [rows][64] fp16, 16B groups XOR-swizzled by
// (row&7). Chunk c covers row=c>>3, group kg=c&7, global col (kg^(row&7))*8;
// LDS dst = c*16 B (wave-uniform base + lane*16 contract of global_load_lds).

template<int NCH, int NT>
__device__ __forceinline__ void init_ptrs(const _Float16* src, int row0, int ld,
                                          const _Float16* gp[NCH]) {
  int t = threadIdx.x;
#pragma unroll
  for (int p = 0; p < NCH; ++p) {
    int c = p * NT + t;
    int row = c >> 3;
    int kg = c & 7;
    int gk = (kg ^ (row & 7)) << 3;
    gp[p] = src + (size_t)(row0 + row) * ld + gk;
  }
}

template<int NCH, int NT>
__device__ __forceinline__ void stage(const _Float16* const gp[NCH], _Float16* ldsbuf) {
  int t = threadIdx.x;
#pragma unroll
  for (int p = 0; p < NCH; ++p)
    __builtin_amdgcn_global_load_lds((gas_ptr)gp[p],
                                     (las_ptr)(ldsbuf + t * 8 + p * NT * 8), 16, 0, 0);
}

template<int NCH>
__device__ __forceinline__ void bump(const _Float16* gp[NCH], int d) {
#pragma unroll
  for (int p = 0; p < NCH; ++p) gp[p] += d;
}

__device__ __forceinline__ half8 frag_ld(const _Float16* lds, int row, int g) {
  return *(const half8*)(lds + row * 64 + ((g ^ (row & 7)) << 3));
}

// 8-wave (2x4) block: wave tile 64x32, per-lane acc 4x2 x floatx4
__device__ __forceinline__ void mfma_tile42(const _Float16* la, const _Float16* lb,
                                            floatx4 acc[4][2], int wm, int wn,
                                            int l16, int quad) {
#pragma unroll
  for (int kf = 0; kf < 2; ++kf) {
    half8 af[4], bf[2];
#pragma unroll
    for (int i = 0; i < 4; ++i) af[i] = frag_ld(la, wm * 64 + i * 16 + l16, kf * 4 + quad);
#pragma unroll
    for (int i = 0; i < 2; ++i) bf[i] = frag_ld(lb, wn * 32 + i * 16 + l16, kf * 4 + quad);
#pragma unroll
    for (int mi = 0; mi < 4; ++mi)
#pragma unroll
      for (int ni = 0; ni < 2; ++ni)
        acc[mi][ni] = __builtin_amdgcn_mfma_f32_16x16x32_f16(af[mi], bf[ni], acc[mi][ni], 0, 0, 0);
  }
}

#define ZERO_ACC42(acc)                                 \
  _Pragma("unroll") for (int mi = 0; mi < 4; ++mi)      \
  _Pragma("unroll") for (int ni = 0; ni < 2; ++ni)      \
  _Pragma("unroll") for (int r = 0; r < 4; ++r) acc[mi][ni][r] = 0.0f;

// ---- pre-pass ----

// x (8,1024,512) fp32 -> x16 (straight fp16) + xT (8,512,1024) fp16
__global__ void x_prep_kernel(const float* __restrict__ in, _Float16* __restrict__ x16,
                              _Float16* __restrict__ xT) {
  __shared__ float tile[32][33];
  const int R = 1024, C = 512;
  int c0 = blockIdx.x * 32, r0 = blockIdx.y * 32;
  size_t boff = (size_t)blockIdx.z * R * C;
  in += boff; x16 += boff; xT += boff;
  int tx = threadIdx.x & 31, ty = threadIdx.x >> 5;  // 32 x 8
#pragma unroll
  for (int i = 0; i < 32; i += 8) {
    float v = in[(size_t)(r0 + ty + i) * C + c0 + tx];
    tile[ty + i][tx] = v;
    x16[(size_t)(r0 + ty + i) * C + c0 + tx] = (_Float16)v;
  }
  __syncthreads();
#pragma unroll
  for (int i = 0; i < 32; i += 8)
    xT[(size_t)(c0 + ty + i) * R + r0 + tx] = (_Float16)tile[tx][ty + i];
}

// z=0: Wp (512,2048)->WpT(2048,512); z=1: Wg (1024,1024)->WgT(1024,1024)
__global__ void w_prep_kernel(const float* __restrict__ Wp, _Float16* __restrict__ WpT,
                              const float* __restrict__ Wg, _Float16* __restrict__ WgT) {
  __shared__ float tile[32][33];
  const float* in; _Float16* out; int R, C, c0, r0;
  if (blockIdx.z == 0) {
    in = Wp; out = WpT; R = 512; C = 2048;
    c0 = blockIdx.x * 32; r0 = blockIdx.y * 32;
  } else {
    in = Wg; out = WgT; R = 1024; C = 1024;
    c0 = (blockIdx.x & 31) * 32; r0 = (blockIdx.y * 2 + (blockIdx.x >> 5)) * 32;
  }
  int tx = threadIdx.x & 31, ty = threadIdx.x >> 5;
#pragma unroll
  for (int i = 0; i < 32; i += 8)
    tile[ty + i][tx] = in[(size_t)(r0 + ty + i) * C + c0 + tx];
  __syncthreads();
#pragma unroll
  for (int i = 0; i < 32; i += 8)
    out[(size_t)(c0 + ty + i) * R + r0 + tx] = (_Float16)tile[tx][ty + i];
}

// ---- K1: y = relu(x @ W_proj + b_proj) -> y_t (B,F,L,H) fp16 ----
// 512 thr, 8 waves (2x4), 128x128 tile, dbuf BK=64. M=8192 N=2048 K=512.

__global__ __launch_bounds__(512, 4) void proj_kernel(const _Float16* __restrict__ x16,
                                                      const _Float16* __restrict__ WpT,
                                                      const float* __restrict__ bp,
                                                      _Float16* __restrict__ y_t) {
  __shared__ __align__(16) _Float16 ldsA[2][128 * 64];
  __shared__ __align__(16) _Float16 ldsB[2][128 * 64];
  int i0 = blockIdx.x * 128, n0 = blockIdx.y * 128;
  int t = threadIdx.x, lane = t & 63, w = t >> 6;
  int wm = w >> 2, wn = w & 3, quad = lane >> 4, l16 = lane & 15;
  const _Float16* gpA[2]; const _Float16* gpB[2];
  init_ptrs<2, 512>(x16, i0, 512, gpA);
  init_ptrs<2, 512>(WpT, n0, 512, gpB);
  floatx4 acc[4][2];
  ZERO_ACC42(acc);
  stage<2, 512>(gpA, ldsA[0]); bump<2>(gpA, 64);
  stage<2, 512>(gpB, ldsB[0]); bump<2>(gpB, 64);
#pragma unroll 1
  for (int kt = 0; kt < 8; ++kt) {
    __syncthreads();
    if (kt < 7) {
      stage<2, 512>(gpA, ldsA[(kt + 1) & 1]); bump<2>(gpA, 64);
      stage<2, 512>(gpB, ldsB[(kt + 1) & 1]); bump<2>(gpB, 64);
    }
    mfma_tile42(ldsA[kt & 1], ldsB[kt & 1], acc, wm, wn, l16, quad);
  }
#pragma unroll
  for (int mi = 0; mi < 4; ++mi)
#pragma unroll
    for (int ni = 0; ni < 2; ++ni)
#pragma unroll
      for (int r = 0; r < 4; ++r) {
        int gr = i0 + wm * 64 + mi * 16 + quad * 4 + r;   // 0..8191
        int gc = n0 + wn * 32 + ni * 16 + l16;            // 0..2047
        float c = fmaxf(acc[mi][ni][r] + bp[gc], 0.0f);
        int b = gr >> 10, l = gr & 1023;
        int f = gc & 3, h = gc >> 2;
        y_t[(((size_t)(b * 4 + f)) * 1024 + l) * 512 + h] = (_Float16)c;
      }
}

// ---- K2: S[b,i,j] = max_f sum_h Y_f[i,h] Y_f[j,h]; S symmetric ----
// 288 blocks (8 b x 36 upper-tri tiles) x 512 thr, all co-resident.
// b = id & 7 XCD pin. Off-diag tiles also write the mirror block via an
// LDS transpose: fp32 tile stride 129 -> transposed reads 2-way bank-aliased
// (free per m136), global stores coalesced. Scalar LDS pointers only (no
// pointer arrays: clang static-initializer addrspacecast bug).

__global__ __launch_bounds__(512, 4) void score_kernel(const _Float16* __restrict__ y_t,
                                                       float* __restrict__ S) {
  __shared__ __align__(16) char smem[128 * 129 * 4];   // 66048 B >= 4x16384 staging
  _Float16* LA0 = (_Float16*)smem;
  _Float16* LA1 = (_Float16*)(smem + 16384);
  _Float16* LB0 = (_Float16*)(smem + 32768);
  _Float16* LB1 = (_Float16*)(smem + 49152);
  int id = blockIdx.x;
  int b = id & 7;
  int tt = id >> 3;            // 0..35 upper-tri tile index
  int ti = 0;
  while (tt >= 8 - ti) { tt -= 8 - ti; ++ti; }
  int tj = ti + tt;
  int i0 = ti * 128, j0 = tj * 128;
  int t = threadIdx.x, lane = t & 63, w = t >> 6;
  int wm = w >> 2, wn = w & 3, quad = lane >> 4, l16 = lane & 15;
  const int PLANE = 1024 * 512;
  const _Float16* base = y_t + (size_t)b * 4 * PLANE;
  const _Float16* gpA[2]; const _Float16* gpB[2];
  init_ptrs<2, 512>(base, i0, 512, gpA);
  init_ptrs<2, 512>(base, j0, 512, gpB);
  floatx4 acc[4][2], smax[4][2];
  ZERO_ACC42(acc);
  stage<2, 512>(gpA, LA0); bump<2>(gpA, 64);
  stage<2, 512>(gpB, LB0); bump<2>(gpB, 64);
#pragma unroll 1
  for (int f = 0; f < 4; ++f) {
#pragma unroll 1
    for (int kt = 0; kt < 8; ++kt) {
      __syncthreads();
      if (f * 8 + kt < 31) {
        if (kt == 7) { bump<2>(gpA, PLANE - 512); bump<2>(gpB, PLANE - 512); }
        stage<2, 512>(gpA, ((kt + 1) & 1) ? LA1 : LA0); bump<2>(gpA, 64);
        stage<2, 512>(gpB, ((kt + 1) & 1) ? LB1 : LB0); bump<2>(gpB, 64);
      }
      mfma_tile42((kt & 1) ? LA1 : LA0, (kt & 1) ? LB1 : LB0, acc, wm, wn, l16, quad);
    }
    if (f == 0) {
#pragma unroll
      for (int mi = 0; mi < 4; ++mi)
#pragma unroll
        for (int ni = 0; ni < 2; ++ni) smax[mi][ni] = acc[mi][ni];
    } else {
#pragma unroll
      for (int mi = 0; mi < 4; ++mi)
#pragma unroll
        for (int ni = 0; ni < 2; ++ni)
#pragma unroll
          for (int r = 0; r < 4; ++r)
            smax[mi][ni][r] = fmaxf(smax[mi][ni][r], acc[mi][ni][r]);
    }
    ZERO_ACC42(acc);
  }
  float* Sb = S + (size_t)b * 1024 * 1024;
  // primary block (i0, j0) straight from registers
#pragma unroll
  for (int mi = 0; mi < 4; ++mi)
#pragma unroll
    for (int ni = 0; ni < 2; ++ni)
#pragma unroll
      for (int r = 0; r < 4; ++r) {
        int gi = i0 + wm * 64 + mi * 16 + quad * 4 + r;
        int gj = j0 + wn * 32 + ni * 16 + l16;
        Sb[(size_t)gi * 1024 + gj] = smax[mi][ni][r];
      }
  if (ti != tj) {
    // mirror block (j0, i0) = primary^T via LDS
    __syncthreads();                 // staging buffers dead
    float* tl = (float*)smem;        // [128][129]
#pragma unroll
    for (int mi = 0; mi < 4; ++mi)
#pragma unroll
      for (int ni = 0; ni < 2; ++ni)
#pragma unroll
        for (int r = 0; r < 4; ++r)
          tl[(wm * 64 + mi * 16 + quad * 4 + r) * 129 + (wn * 32 + ni * 16 + l16)] =
              smax[mi][ni][r];
    __syncthreads();
#pragma unroll 1
    for (int k = 0; k < 32; ++k) {
      int flat = k * 512 + t;
      int rm = flat >> 7, cm = flat & 127;   // mirror row (=local j), col (=local i)
      Sb[(size_t)(j0 + rm) * 1024 + (i0 + cm)] = tl[cm * 129 + rm];
    }
  }
}

// ---- K3: allennlp masked softmax per row -> alpha fp16 ----
// p = softmax(logits*m) (masked entries participate as 0), alpha = p*m/(sum(p*m)+1e-13)

__global__ __launch_bounds__(256) void softmax_kernel(const float* __restrict__ S,
                                                      const int* __restrict__ xmask,
                                                      _Float16* __restrict__ alpha) {
  __shared__ float red[16];
  int row = blockIdx.x;               // 0..8191
  int b = row >> 10, l = row & 1023;
  const float* sr = S + (size_t)row * 1024;
  const int* mr = xmask + b * 1024;
  int t = threadIdx.x, lane = t & 63, wid = t >> 6;
  int rm = mr[l];
  float v[4], mm[4];
  float vmax = 0.0f;  // masked entries are exactly 0, so max >= 0 always
#pragma unroll
  for (int q = 0; q < 4; ++q) {
    int i = t + q * 256;
    int m = (rm && mr[i] && (i != l)) ? 1 : 0;
    mm[q] = (float)m;
    v[q] = m ? sr[i] : 0.0f;
    vmax = fmaxf(vmax, v[q]);
  }
  for (int off = 32; off; off >>= 1) vmax = fmaxf(vmax, __shfl_down(vmax, off));
  if (lane == 0) red[wid] = vmax;
  __syncthreads();
  if (t == 0) red[8] = fmaxf(fmaxf(red[0], red[1]), fmaxf(red[2], red[3]));
  __syncthreads();
  vmax = red[8];
  float e[4], E = 0.0f, E2 = 0.0f;
#pragma unroll
  for (int q = 0; q < 4; ++q) {
    e[q] = expf(v[q] - vmax);
    E += e[q];
    E2 += e[q] * mm[q];
  }
  for (int off = 32; off; off >>= 1) {
    E += __shfl_down(E, off);
    E2 += __shfl_down(E2, off);
  }
  if (lane == 0) { red[wid] = E; red[4 + wid] = E2; }
  __syncthreads();
  if (t == 0) {
    red[9] = red[0] + red[1] + red[2] + red[3];
    red[10] = red[4] + red[5] + red[6] + red[7];
  }
  __syncthreads();
  E = red[9]; E2 = red[10];
  float inv = 1.0f / (E2 + 1e-13f * E);
  _Float16* ar = alpha + (size_t)row * 1024;
#pragma unroll
  for (int q = 0; q < 4; ++q) {
    int i = t + q * 256;
    ar[i] = (_Float16)(e[q] * mm[q] * inv);
  }
}

// ---- K4: enc[b] = alpha[b] @ x[b]  (xT (B,H,L) as B-operand) ----
// 512 blocks x 256 thr: 64-row i-tiles x 4 n-tiles x 8 b; b = id & 7 XCD pin.

__global__ __launch_bounds__(256) void attn_kernel(const _Float16* __restrict__ alpha,
                                                   const _Float16* __restrict__ xT,
                                                   _Float16* __restrict__ enc) {
  __shared__ __align__(16) _Float16 ldsA[2][64 * 64];
  __shared__ __align__(16) _Float16 ldsB[2][128 * 64];
  int id = blockIdx.x;
  int b = id & 7;
  int r2 = id >> 3;                 // 0..63
  int i0 = (r2 >> 2) * 64;          // 16 i-tiles of 64
  int n0 = (r2 & 3) * 128;          // 4 n-tiles of 128
  const _Float16* A = alpha + (size_t)b * 1024 * 1024;
  const _Float16* Bm = xT + (size_t)b * 512 * 1024;
  int t = threadIdx.x, lane = t & 63, wn = t >> 6;   // wave grid 1x4
  int quad = lane >> 4, l16 = lane & 15;
  const _Float16* gpA[2]; const _Float16* gpB[4];
  init_ptrs<2, 256>(A, i0, 1024, gpA);
  init_ptrs<4, 256>(Bm, n0, 1024, gpB);
  floatx4 acc[4][2];
  ZERO_ACC42(acc);
  stage<2, 256>(gpA, ldsA[0]); bump<2>(gpA, 64);
  stage<4, 256>(gpB, ldsB[0]); bump<4>(gpB, 64);
#pragma unroll 1
  for (int kt = 0; kt < 16; ++kt) {
    __syncthreads();
    if (kt < 15) {
      stage<2, 256>(gpA, ldsA[(kt + 1) & 1]); bump<2>(gpA, 64);
      stage<4, 256>(gpB, ldsB[(kt + 1) & 1]); bump<4>(gpB, 64);
    }
    const _Float16* la = ldsA[kt & 1];
    const _Float16* lb = ldsB[kt & 1];
#pragma unroll
    for (int kf = 0; kf < 2; ++kf) {
      half8 af[4], bf[2];
#pragma unroll
      for (int i = 0; i < 4; ++i) af[i] = frag_ld(la, i * 16 + l16, kf * 4 + quad);
#pragma unroll
      for (int i = 0; i < 2; ++i) bf[i] = frag_ld(lb, wn * 32 + i * 16 + l16, kf * 4 + quad);
#pragma unroll
      for (int mi = 0; mi < 4; ++mi)
#pragma unroll
        for (int ni = 0; ni < 2; ++ni)
          acc[mi][ni] = __builtin_amdgcn_mfma_f32_16x16x32_f16(af[mi], bf[ni], acc[mi][ni], 0, 0, 0);
    }
  }
  _Float16* eb = enc + (size_t)b * 1024 * 512;
#pragma unroll
  for (int mi = 0; mi < 4; ++mi)
#pragma unroll
    for (int ni = 0; ni < 2; ++ni)
#pragma unroll
      for (int r = 0; r < 4; ++r) {
        int gr = i0 + mi * 16 + quad * 4 + r;            // l
        int gc = n0 + wn * 32 + ni * 16 + l16;           // h
        eb[(size_t)gr * 512 + gc] = (_Float16)acc[mi][ni][r];
      }
}

// ---- K5: gate = sigmoid([x|enc] @ W_gate + b_gate); out = gate*[x16|enc] ----
// 512 thr, 8 waves. grid (64,8): i0 on x so XCD k caches its A-tiles + all B.

__global__ __launch_bounds__(512, 4) void gate_kernel(const _Float16* __restrict__ x16,
                                                      const _Float16* __restrict__ enc,
                                                      const _Float16* __restrict__ WgT,
                                                      const float* __restrict__ bg,
                                                      float* __restrict__ out) {
  __shared__ __align__(16) _Float16 ldsA[2][128 * 64];
  __shared__ __align__(16) _Float16 ldsB[2][128 * 64];
  int i0 = blockIdx.x * 128, n0 = blockIdx.y * 128;
  int t = threadIdx.x, lane = t & 63, w = t >> 6;
  int wm = w >> 2, wn = w & 3, quad = lane >> 4, l16 = lane & 15;
  const _Float16* gpA[2]; const _Float16* gpA2[2]; const _Float16* gpB[2];
  init_ptrs<2, 512>(x16, i0, 512, gpA);
  init_ptrs<2, 512>(enc, i0, 512, gpA2);
  init_ptrs<2, 512>(WgT, n0, 1024, gpB);
  floatx4 acc[4][2];
  ZERO_ACC42(acc);
  stage<2, 512>(gpA, ldsA[0]); bump<2>(gpA, 64);
  stage<2, 512>(gpB, ldsB[0]); bump<2>(gpB, 64);
#pragma unroll 1
  for (int kt = 0; kt < 16; ++kt) {
    __syncthreads();
    if (kt < 15) {
      if (kt < 7) { stage<2, 512>(gpA,  ldsA[(kt + 1) & 1]); bump<2>(gpA, 64); }
      else        { stage<2, 512>(gpA2, ldsA[(kt + 1) & 1]); bump<2>(gpA2, 64); }
      stage<2, 512>(gpB, ldsB[(kt + 1) & 1]); bump<2>(gpB, 64);
    }
    mfma_tile42(ldsA[kt & 1], ldsB[kt & 1], acc, wm, wn, l16, quad);
  }
#pragma unroll
  for (int mi = 0; mi < 4; ++mi)
#pragma unroll
    for (int ni = 0; ni < 2; ++ni)
#pragma unroll
      for (int r = 0; r < 4; ++r) {
        int gr = i0 + wm * 64 + mi * 16 + quad * 4 + r;  // 0..8191
        int gc = n0 + wn * 32 + ni * 16 + l16;           // 0..1023
        float c = acc[mi][ni][r] + bg[gc];
        float g = 1.0f / (1.0f + expf(-c));
        float jv = (gc < 512) ? (float)x16[(size_t)gr * 512 + gc]
                              : (float)enc[(size_t)gr * 512 + (gc - 512)];
        out[(size_t)gr * 1024 + gc] = g * jv;
      }
}

// ---- launch ----

extern "C" void kernel_launch(void* const* d_in, const int* in_sizes, int n_in,
                              void* d_out, int out_size, void* d_ws, size_t ws_size,
                              hipStream_t stream) {
  const float* x  = (const float*)d_in[0];   // (8,1024,512)
  const int* xm   = (const int*)d_in[1];     // (8,1024)
  const float* Wp = (const float*)d_in[2];   // (512,2048)
  const float* bp = (const float*)d_in[3];   // (2048)
  const float* Wg = (const float*)d_in[4];   // (1024,1024)
  const float* bg = (const float*)d_in[5];   // (1024)
  float* out = (float*)d_out;

  char* ws = (char*)d_ws;
  const size_t MB = 1024 * 1024;
  _Float16* x16 = (_Float16*)(ws);            // 8 MB  (8192,512)
  _Float16* xT  = (_Float16*)(ws + 8 * MB);   // 8 MB  (8,512,1024)
  _Float16* WpT = (_Float16*)(ws + 16 * MB);  // 2 MB  (2048,512)
  _Float16* WgT = (_Float16*)(ws + 18 * MB);  // 2 MB  (1024,1024)
  _Float16* y_t = (_Float16*)(ws + 20 * MB);  // 32 MB (8,4,1024,512)
  float*    S   = (float*)(ws + 52 * MB);     // 32 MB (8,1024,1024)  [end: 84 MB]
  // y_t is dead after score_kernel: alias alpha/enc onto it
  _Float16* alpha = (_Float16*)(ws + 20 * MB); // 16 MB (8,1024,1024)
  _Float16* enc   = (_Float16*)(ws + 36 * MB); // 8 MB  (8,1024,512)

  x_prep_kernel<<<dim3(16, 32, 8), 256, 0, stream>>>(x, x16, xT);
  w_prep_kernel<<<dim3(64, 16, 2), 256, 0, stream>>>(Wp, WpT, Wg, WgT);

  proj_kernel<<<dim3(64, 16), 512, 0, stream>>>(x16, WpT, bp, y_t);
  score_kernel<<<288, 512, 0, stream>>>(y_t, S);
  softmax_kernel<<<8192, 256, 0, stream>>>(S, xm, alpha);
  attn_kernel<<<512, 256, 0, stream>>>(alpha, xT, enc);
  gate_kernel<<<dim3(64, 8), 512, 0, stream>>>(x16, enc, WgT, bg, out);
}

// Round 10
// 216.871 us; speedup vs baseline: 1.3033x; 1.0016x over previous
//
#include <hip/hip_runtime.h>

// Problem constants: B=8, L=1024, H=512, F=4
// out = gate * [x | alpha @ x],  gate = sigmoid([x|enc] @ W_gate)
// alpha = masked_softmax(max_f(Y_f Y_f^T)),  Y = relu(x @ W_proj)
//
// Round 10: proj/gate reverted to r7's 256-thr 4-wave 64x64-wave-tile form
// (r9's 512-thr port raised LDS-read traffic/FLOP by 50% -- regression for
// these throughput-bound short-K kernels; data: score gained >=4.4 us yet
// total moved only -3). Score keeps r9 symmetry (36/64 tiles + LDS-transpose
// mirror); attn/softmax/prep unchanged.

typedef _Float16 half8 __attribute__((ext_vector_type(8)));
typedef float floatx4 __attribute__((ext_vector_type(4)));

typedef const __attribute__((address_space(1))) void* gas_ptr;
typedef __attribute__((address_space(3))) void* las_ptr;

// ---- staging machinery ----
// LDS tile layout: row-major [rows][64] fp16, 16B groups XOR-swizzled by
// (row&7). Chunk c covers row=c>>3, group kg=c&7, global col (kg^(row&7))*8;
// LDS dst = c*16 B (wave-uniform base + lane*16 contract of global_load_lds).

template<int NCH, int NT>
__device__ __forceinline__ void init_ptrs(const _Float16* src, int row0, int ld,
                                          const _Float16* gp[NCH]) {
  int t = threadIdx.x;
#pragma unroll
  for (int p = 0; p < NCH; ++p) {
    int c = p * NT + t;
    int row = c >> 3;
    int kg = c & 7;
    int gk = (kg ^ (row & 7)) << 3;
    gp[p] = src + (size_t)(row0 + row) * ld + gk;
  }
}

template<int NCH, int NT>
__device__ __forceinline__ void stage(const _Float16* const gp[NCH], _Float16* ldsbuf) {
  int t = threadIdx.x;
#pragma unroll
  for (int p = 0; p < NCH; ++p)
    __builtin_amdgcn_global_load_lds((gas_ptr)gp[p],
                                     (las_ptr)(ldsbuf + t * 8 + p * NT * 8), 16, 0, 0);
}

template<int NCH>
__device__ __forceinline__ void bump(const _Float16* gp[NCH], int d) {
#pragma unroll
  for (int p = 0; p < NCH; ++p) gp[p] += d;
}

__device__ __forceinline__ half8 frag_ld(const _Float16* lds, int row, int g) {
  return *(const half8*)(lds + row * 64 + ((g ^ (row & 7)) << 3));
}

// 4-wave (2x2) block: wave tile 64x64, per-lane acc 4x4 (B-frag reuse 4x --
// lowest LDS-read traffic per FLOP; use for throughput-bound short-K GEMMs)
__device__ __forceinline__ void mfma_tile44(const _Float16* lds_a, const _Float16* lds_b,
                                            floatx4 acc[4][4], int wm, int wn,
                                            int l16, int quad) {
#pragma unroll
  for (int kf = 0; kf < 2; ++kf) {
    half8 af[4], bf[4];
#pragma unroll
    for (int i = 0; i < 4; ++i) af[i] = frag_ld(lds_a, wm * 64 + i * 16 + l16, kf * 4 + quad);
#pragma unroll
    for (int i = 0; i < 4; ++i) bf[i] = frag_ld(lds_b, wn * 64 + i * 16 + l16, kf * 4 + quad);
#pragma unroll
    for (int mi = 0; mi < 4; ++mi)
#pragma unroll
      for (int ni = 0; ni < 4; ++ni)
        acc[mi][ni] = __builtin_amdgcn_mfma_f32_16x16x32_f16(af[mi], bf[ni], acc[mi][ni], 0, 0, 0);
  }
}

#define ZERO_ACC44(acc)                                 \
  _Pragma("unroll") for (int mi = 0; mi < 4; ++mi)      \
  _Pragma("unroll") for (int ni = 0; ni < 4; ++ni)      \
  _Pragma("unroll") for (int r = 0; r < 4; ++r) acc[mi][ni][r] = 0.0f;

// 8-wave (2x4) block: wave tile 64x32, per-lane acc 4x2 (max waves/CU --
// use for latency-bound long-K loops)
__device__ __forceinline__ void mfma_tile42(const _Float16* la, const _Float16* lb,
                                            floatx4 acc[4][2], int wm, int wn,
                                            int l16, int quad) {
#pragma unroll
  for (int kf = 0; kf < 2; ++kf) {
    half8 af[4], bf[2];
#pragma unroll
    for (int i = 0; i < 4; ++i) af[i] = frag_ld(la, wm * 64 + i * 16 + l16, kf * 4 + quad);
#pragma unroll
    for (int i = 0; i < 2; ++i) bf[i] = frag_ld(lb, wn * 32 + i * 16 + l16, kf * 4 + quad);
#pragma unroll
    for (int mi = 0; mi < 4; ++mi)
#pragma unroll
      for (int ni = 0; ni < 2; ++ni)
        acc[mi][ni] = __builtin_amdgcn_mfma_f32_16x16x32_f16(af[mi], bf[ni], acc[mi][ni], 0, 0, 0);
  }
}

#define ZERO_ACC42(acc)                                 \
  _Pragma("unroll") for (int mi = 0; mi < 4; ++mi)      \
  _Pragma("unroll") for (int ni = 0; ni < 2; ++ni)      \
  _Pragma("unroll") for (int r = 0; r < 4; ++r) acc[mi][ni][r] = 0.0f;

// ---- pre-pass ----

// x (8,1024,512) fp32 -> x16 (straight fp16) + xT (8,512,1024) fp16
__global__ void x_prep_kernel(const float* __restrict__ in, _Float16* __restrict__ x16,
                              _Float16* __restrict__ xT) {
  __shared__ float tile[32][33];
  const int R = 1024, C = 512;
  int c0 = blockIdx.x * 32, r0 = blockIdx.y * 32;
  size_t boff = (size_t)blockIdx.z * R * C;
  in += boff; x16 += boff; xT += boff;
  int tx = threadIdx.x & 31, ty = threadIdx.x >> 5;  // 32 x 8
#pragma unroll
  for (int i = 0; i < 32; i += 8) {
    float v = in[(size_t)(r0 + ty + i) * C + c0 + tx];
    tile[ty + i][tx] = v;
    x16[(size_t)(r0 + ty + i) * C + c0 + tx] = (_Float16)v;
  }
  __syncthreads();
#pragma unroll
  for (int i = 0; i < 32; i += 8)
    xT[(size_t)(c0 + ty + i) * R + r0 + tx] = (_Float16)tile[tx][ty + i];
}

// z=0: Wp (512,2048)->WpT(2048,512); z=1: Wg (1024,1024)->WgT(1024,1024)
__global__ void w_prep_kernel(const float* __restrict__ Wp, _Float16* __restrict__ WpT,
                              const float* __restrict__ Wg, _Float16* __restrict__ WgT) {
  __shared__ float tile[32][33];
  const float* in; _Float16* out; int R, C, c0, r0;
  if (blockIdx.z == 0) {
    in = Wp; out = WpT; R = 512; C = 2048;
    c0 = blockIdx.x * 32; r0 = blockIdx.y * 32;
  } else {
    in = Wg; out = WgT; R = 1024; C = 1024;
    c0 = (blockIdx.x & 31) * 32; r0 = (blockIdx.y * 2 + (blockIdx.x >> 5)) * 32;
  }
  int tx = threadIdx.x & 31, ty = threadIdx.x >> 5;
#pragma unroll
  for (int i = 0; i < 32; i += 8)
    tile[ty + i][tx] = in[(size_t)(r0 + ty + i) * C + c0 + tx];
  __syncthreads();
#pragma unroll
  for (int i = 0; i < 32; i += 8)
    out[(size_t)(c0 + ty + i) * R + r0 + tx] = (_Float16)tile[tx][ty + i];
}

// ---- K1: y = relu(x @ W_proj + b_proj) -> y_t (B,F,L,H) fp16 ----
// 256 thr, 2x2 waves, 128x128 tile, dbuf BK=64 (r7-proven shape).

__global__ __launch_bounds__(256) void proj_kernel(const _Float16* __restrict__ x16,
                                                   const _Float16* __restrict__ WpT,
                                                   const float* __restrict__ bp,
                                                   _Float16* __restrict__ y_t) {
  __shared__ __align__(16) _Float16 ldsA[2][128 * 64];
  __shared__ __align__(16) _Float16 ldsB[2][128 * 64];
  int i0 = blockIdx.x * 128, n0 = blockIdx.y * 128;
  int t = threadIdx.x, lane = t & 63, w = t >> 6;
  int wm = w >> 1, wn = w & 1, quad = lane >> 4, l16 = lane & 15;
  const _Float16* gpA[4]; const _Float16* gpB[4];
  init_ptrs<4, 256>(x16, i0, 512, gpA);
  init_ptrs<4, 256>(WpT, n0, 512, gpB);
  floatx4 acc[4][4];
  ZERO_ACC44(acc);
  stage<4, 256>(gpA, ldsA[0]); bump<4>(gpA, 64);
  stage<4, 256>(gpB, ldsB[0]); bump<4>(gpB, 64);
#pragma unroll 1
  for (int kt = 0; kt < 8; ++kt) {
    __syncthreads();
    if (kt < 7) {
      stage<4, 256>(gpA, ldsA[(kt + 1) & 1]); bump<4>(gpA, 64);
      stage<4, 256>(gpB, ldsB[(kt + 1) & 1]); bump<4>(gpB, 64);
    }
    mfma_tile44(ldsA[kt & 1], ldsB[kt & 1], acc, wm, wn, l16, quad);
  }
#pragma unroll
  for (int mi = 0; mi < 4; ++mi)
#pragma unroll
    for (int ni = 0; ni < 4; ++ni)
#pragma unroll
      for (int r = 0; r < 4; ++r) {
        int gr = i0 + wm * 64 + mi * 16 + quad * 4 + r;   // 0..8191
        int gc = n0 + wn * 64 + ni * 16 + l16;            // 0..2047
        float c = fmaxf(acc[mi][ni][r] + bp[gc], 0.0f);
        int b = gr >> 10, l = gr & 1023;
        int f = gc & 3, h = gc >> 2;
        y_t[(((size_t)(b * 4 + f)) * 1024 + l) * 512 + h] = (_Float16)c;
      }
}

// ---- K2: S[b,i,j] = max_f sum_h Y_f[i,h] Y_f[j,h]; S symmetric ----
// 288 blocks (8 b x 36 upper-tri tiles) x 512 thr. b = id & 7 XCD pin.
// Off-diag tiles write the mirror block via LDS transpose (stride-129 fp32).
// Scalar LDS pointers only (pointer arrays of LDS fail to compile).

__global__ __launch_bounds__(512, 4) void score_kernel(const _Float16* __restrict__ y_t,
                                                       float* __restrict__ S) {
  __shared__ __align__(16) char smem[128 * 129 * 4];   // 66048 B >= 4x16384 staging
  _Float16* LA0 = (_Float16*)smem;
  _Float16* LA1 = (_Float16*)(smem + 16384);
  _Float16* LB0 = (_Float16*)(smem + 32768);
  _Float16* LB1 = (_Float16*)(smem + 49152);
  int id = blockIdx.x;
  int b = id & 7;
  int tt = id >> 3;            // 0..35 upper-tri tile index
  int ti = 0;
  while (tt >= 8 - ti) { tt -= 8 - ti; ++ti; }
  int tj = ti + tt;
  int i0 = ti * 128, j0 = tj * 128;
  int t = threadIdx.x, lane = t & 63, w = t >> 6;
  int wm = w >> 2, wn = w & 3, quad = lane >> 4, l16 = lane & 15;
  const int PLANE = 1024 * 512;
  const _Float16* base = y_t + (size_t)b * 4 * PLANE;
  const _Float16* gpA[2]; const _Float16* gpB[2];
  init_ptrs<2, 512>(base, i0, 512, gpA);
  init_ptrs<2, 512>(base, j0, 512, gpB);
  floatx4 acc[4][2], smax[4][2];
  ZERO_ACC42(acc);
  stage<2, 512>(gpA, LA0); bump<2>(gpA, 64);
  stage<2, 512>(gpB, LB0); bump<2>(gpB, 64);
#pragma unroll 1
  for (int f = 0; f < 4; ++f) {
#pragma unroll 1
    for (int kt = 0; kt < 8; ++kt) {
      __syncthreads();
      if (f * 8 + kt < 31) {
        if (kt == 7) { bump<2>(gpA, PLANE - 512); bump<2>(gpB, PLANE - 512); }
        stage<2, 512>(gpA, ((kt + 1) & 1) ? LA1 : LA0); bump<2>(gpA, 64);
        stage<2, 512>(gpB, ((kt + 1) & 1) ? LB1 : LB0); bump<2>(gpB, 64);
      }
      mfma_tile42((kt & 1) ? LA1 : LA0, (kt & 1) ? LB1 : LB0, acc, wm, wn, l16, quad);
    }
    if (f == 0) {
#pragma unroll
      for (int mi = 0; mi < 4; ++mi)
#pragma unroll
        for (int ni = 0; ni < 2; ++ni) smax[mi][ni] = acc[mi][ni];
    } else {
#pragma unroll
      for (int mi = 0; mi < 4; ++mi)
#pragma unroll
        for (int ni = 0; ni < 2; ++ni)
#pragma unroll
          for (int r = 0; r < 4; ++r)
            smax[mi][ni][r] = fmaxf(smax[mi][ni][r], acc[mi][ni][r]);
    }
    ZERO_ACC42(acc);
  }
  float* Sb = S + (size_t)b * 1024 * 1024;
  // primary block (i0, j0) straight from registers
#pragma unroll
  for (int mi = 0; mi < 4; ++mi)
#pragma unroll
    for (int ni = 0; ni < 2; ++ni)
#pragma unroll
      for (int r = 0; r < 4; ++r) {
        int gi = i0 + wm * 64 + mi * 16 + quad * 4 + r;
        int gj = j0 + wn * 32 + ni * 16 + l16;
        Sb[(size_t)gi * 1024 + gj] = smax[mi][ni][r];
      }
  if (ti != tj) {
    // mirror block (j0, i0) = primary^T via LDS
    __syncthreads();                 // staging buffers dead
    float* tl = (float*)smem;        // [128][129]
#pragma unroll
    for (int mi = 0; mi < 4; ++mi)
#pragma unroll
      for (int ni = 0; ni < 2; ++ni)
#pragma unroll
        for (int r = 0; r < 4; ++r)
          tl[(wm * 64 + mi * 16 + quad * 4 + r) * 129 + (wn * 32 + ni * 16 + l16)] =
              smax[mi][ni][r];
    __syncthreads();
#pragma unroll 1
    for (int k = 0; k < 32; ++k) {
      int flat = k * 512 + t;
      int rm = flat >> 7, cm = flat & 127;   // mirror row (=local j), col (=local i)
      Sb[(size_t)(j0 + rm) * 1024 + (i0 + cm)] = tl[cm * 129 + rm];
    }
  }
}

// ---- K3: allennlp masked softmax per row -> alpha fp16 ----
// p = softmax(logits*m) (masked entries participate as 0), alpha = p*m/(sum(p*m)+1e-13)

__global__ __launch_bounds__(256) void softmax_kernel(const float* __restrict__ S,
                                                      const int* __restrict__ xmask,
                                                      _Float16* __restrict__ alpha) {
  __shared__ float red[16];
  int row = blockIdx.x;               // 0..8191
  int b = row >> 10, l = row & 1023;
  const float* sr = S + (size_t)row * 1024;
  const int* mr = xmask + b * 1024;
  int t = threadIdx.x, lane = t & 63, wid = t >> 6;
  int rm = mr[l];
  float v[4], mm[4];
  float vmax = 0.0f;  // masked entries are exactly 0, so max >= 0 always
#pragma unroll
  for (int q = 0; q < 4; ++q) {
    int i = t + q * 256;
    int m = (rm && mr[i] && (i != l)) ? 1 : 0;
    mm[q] = (float)m;
    v[q] = m ? sr[i] : 0.0f;
    vmax = fmaxf(vmax, v[q]);
  }
  for (int off = 32; off; off >>= 1) vmax = fmaxf(vmax, __shfl_down(vmax, off));
  if (lane == 0) red[wid] = vmax;
  __syncthreads();
  if (t == 0) red[8] = fmaxf(fmaxf(red[0], red[1]), fmaxf(red[2], red[3]));
  __syncthreads();
  vmax = red[8];
  float e[4], E = 0.0f, E2 = 0.0f;
#pragma unroll
  for (int q = 0; q < 4; ++q) {
    e[q] = expf(v[q] - vmax);
    E += e[q];
    E2 += e[q] * mm[q];
  }
  for (int off = 32; off; off >>= 1) {
    E += __shfl_down(E, off);
    E2 += __shfl_down(E2, off);
  }
  if (lane == 0) { red[wid] = E; red[4 + wid] = E2; }
  __syncthreads();
  if (t == 0) {
    red[9] = red[0] + red[1] + red[2] + red[3];
    red[10] = red[4] + red[5] + red[6] + red[7];
  }
  __syncthreads();
  E = red[9]; E2 = red[10];
  float inv = 1.0f / (E2 + 1e-13f * E);
  _Float16* ar = alpha + (size_t)row * 1024;
#pragma unroll
  for (int q = 0; q < 4; ++q) {
    int i = t + q * 256;
    ar[i] = (_Float16)(e[q] * mm[q] * inv);
  }
}

// ---- K4: enc[b] = alpha[b] @ x[b]  (xT (B,H,L) as B-operand) ----
// 512 blocks x 256 thr: 64-row i-tiles x 4 n-tiles x 8 b; b = id & 7 XCD pin.

__global__ __launch_bounds__(256) void attn_kernel(const _Float16* __restrict__ alpha,
                                                   const _Float16* __restrict__ xT,
                                                   _Float16* __restrict__ enc) {
  __shared__ __align__(16) _Float16 ldsA[2][64 * 64];
  __shared__ __align__(16) _Float16 ldsB[2][128 * 64];
  int id = blockIdx.x;
  int b = id & 7;
  int r2 = id >> 3;                 // 0..63
  int i0 = (r2 >> 2) * 64;          // 16 i-tiles of 64
  int n0 = (r2 & 3) * 128;          // 4 n-tiles of 128
  const _Float16* A = alpha + (size_t)b * 1024 * 1024;
  const _Float16* Bm = xT + (size_t)b * 512 * 1024;
  int t = threadIdx.x, lane = t & 63, wn = t >> 6;   // wave grid 1x4
  int quad = lane >> 4, l16 = lane & 15;
  const _Float16* gpA[2]; const _Float16* gpB[4];
  init_ptrs<2, 256>(A, i0, 1024, gpA);
  init_ptrs<4, 256>(Bm, n0, 1024, gpB);
  floatx4 acc[4][2];
  ZERO_ACC42(acc);
  stage<2, 256>(gpA, ldsA[0]); bump<2>(gpA, 64);
  stage<4, 256>(gpB, ldsB[0]); bump<4>(gpB, 64);
#pragma unroll 1
  for (int kt = 0; kt < 16; ++kt) {
    __syncthreads();
    if (kt < 15) {
      stage<2, 256>(gpA, ldsA[(kt + 1) & 1]); bump<2>(gpA, 64);
      stage<4, 256>(gpB, ldsB[(kt + 1) & 1]); bump<4>(gpB, 64);
    }
    const _Float16* la = ldsA[kt & 1];
    const _Float16* lb = ldsB[kt & 1];
#pragma unroll
    for (int kf = 0; kf < 2; ++kf) {
      half8 af[4], bf[2];
#pragma unroll
      for (int i = 0; i < 4; ++i) af[i] = frag_ld(la, i * 16 + l16, kf * 4 + quad);
#pragma unroll
      for (int i = 0; i < 2; ++i) bf[i] = frag_ld(lb, wn * 32 + i * 16 + l16, kf * 4 + quad);
#pragma unroll
      for (int mi = 0; mi < 4; ++mi)
#pragma unroll
        for (int ni = 0; ni < 2; ++ni)
          acc[mi][ni] = __builtin_amdgcn_mfma_f32_16x16x32_f16(af[mi], bf[ni], acc[mi][ni], 0, 0, 0);
    }
  }
  _Float16* eb = enc + (size_t)b * 1024 * 512;
#pragma unroll
  for (int mi = 0; mi < 4; ++mi)
#pragma unroll
    for (int ni = 0; ni < 2; ++ni)
#pragma unroll
      for (int r = 0; r < 4; ++r) {
        int gr = i0 + mi * 16 + quad * 4 + r;            // l
        int gc = n0 + wn * 32 + ni * 16 + l16;           // h
        eb[(size_t)gr * 512 + gc] = (_Float16)acc[mi][ni][r];
      }
}

// ---- K5: gate = sigmoid([x|enc] @ W_gate + b_gate); out = gate*[x16|enc] ----
// 256 thr, 2x2 waves (r7-proven). grid (64,8): i0 on x for XCD L2 locality.

__global__ __launch_bounds__(256) void gate_kernel(const _Float16* __restrict__ x16,
                                                   const _Float16* __restrict__ enc,
                                                   const _Float16* __restrict__ WgT,
                                                   const float* __restrict__ bg,
                                                   float* __restrict__ out) {
  __shared__ __align__(16) _Float16 ldsA[2][128 * 64];
  __shared__ __align__(16) _Float16 ldsB[2][128 * 64];
  int i0 = blockIdx.x * 128, n0 = blockIdx.y * 128;
  int t = threadIdx.x, lane = t & 63, w = t >> 6;
  int wm = w >> 1, wn = w & 1, quad = lane >> 4, l16 = lane & 15;
  const _Float16* gpA[4]; const _Float16* gpA2[4]; const _Float16* gpB[4];
  init_ptrs<4, 256>(x16, i0, 512, gpA);
  init_ptrs<4, 256>(enc, i0, 512, gpA2);
  init_ptrs<4, 256>(WgT, n0, 1024, gpB);
  floatx4 acc[4][4];
  ZERO_ACC44(acc);
  stage<4, 256>(gpA, ldsA[0]); bump<4>(gpA, 64);
  stage<4, 256>(gpB, ldsB[0]); bump<4>(gpB, 64);
  // A prefetch for step kt+1: kt<7 -> x16 tile kt+1; kt=7..14 -> enc tile kt-7.
#pragma unroll 1
  for (int kt = 0; kt < 16; ++kt) {
    __syncthreads();
    if (kt < 15) {
      if (kt < 7) { stage<4, 256>(gpA,  ldsA[(kt + 1) & 1]); bump<4>(gpA, 64); }
      else        { stage<4, 256>(gpA2, ldsA[(kt + 1) & 1]); bump<4>(gpA2, 64); }
      stage<4, 256>(gpB, ldsB[(kt + 1) & 1]); bump<4>(gpB, 64);
    }
    mfma_tile44(ldsA[kt & 1], ldsB[kt & 1], acc, wm, wn, l16, quad);
  }
#pragma unroll
  for (int mi = 0; mi < 4; ++mi)
#pragma unroll
    for (int ni = 0; ni < 4; ++ni)
#pragma unroll
      for (int r = 0; r < 4; ++r) {
        int gr = i0 + wm * 64 + mi * 16 + quad * 4 + r;  // 0..8191
        int gc = n0 + wn * 64 + ni * 16 + l16;           // 0..1023
        float c = acc[mi][ni][r] + bg[gc];
        float g = 1.0f / (1.0f + expf(-c));
        float jv = (gc < 512) ? (float)x16[(size_t)gr * 512 + gc]
                              : (float)enc[(size_t)gr * 512 + (gc - 512)];
        out[(size_t)gr * 1024 + gc] = g * jv;
      }
}

// ---- launch ----

extern "C" void kernel_launch(void* const* d_in, const int* in_sizes, int n_in,
                              void* d_out, int out_size, void* d_ws, size_t ws_size,
                              hipStream_t stream) {
  const float* x  = (const float*)d_in[0];   // (8,1024,512)
  const int* xm   = (const int*)d_in[1];     // (8,1024)
  const float* Wp = (const float*)d_in[2];   // (512,2048)
  const float* bp = (const float*)d_in[3];   // (2048)
  const float* Wg = (const float*)d_in[4];   // (1024,1024)
  const float* bg = (const float*)d_in[5];   // (1024)
  float* out = (float*)d_out;

  char* ws = (char*)d_ws;
  const size_t MB = 1024 * 1024;
  _Float16* x16 = (_Float16*)(ws);            // 8 MB  (8192,512)
  _Float16* xT  = (_Float16*)(ws + 8 * MB);   // 8 MB  (8,512,1024)
  _Float16* WpT = (_Float16*)(ws + 16 * MB);  // 2 MB  (2048,512)
  _Float16* WgT = (_Float16*)(ws + 18 * MB);  // 2 MB  (1024,1024)
  _Float16* y_t = (_Float16*)(ws + 20 * MB);  // 32 MB (8,4,1024,512)
  float*    S   = (float*)(ws + 52 * MB);     // 32 MB (8,1024,1024)  [end: 84 MB]
  // y_t is dead after score_kernel: alias alpha/enc onto it
  _Float16* alpha = (_Float16*)(ws + 20 * MB); // 16 MB (8,1024,1024)
  _Float16* enc   = (_Float16*)(ws + 36 * MB); // 8 MB  (8,1024,512)

  x_prep_kernel<<<dim3(16, 32, 8), 256, 0, stream>>>(x, x16, xT);
  w_prep_kernel<<<dim3(64, 16, 2), 256, 0, stream>>>(Wp, WpT, Wg, WgT);

  proj_kernel<<<dim3(64, 16), 256, 0, stream>>>(x16, WpT, bp, y_t);
  score_kernel<<<288, 512, 0, stream>>>(y_t, S);
  softmax_kernel<<<8192, 256, 0, stream>>>(S, xm, alpha);
  attn_kernel<<<512, 256, 0, stream>>>(alpha, xT, enc);
  gate_kernel<<<dim3(64, 8), 256, 0, stream>>>(x16, enc, WgT, bg, out);
}